// Round 3
// baseline (6055.362 us; speedup 1.0000x reference)
//
#include <hip/hip_runtime.h>
#include <math.h>

// Problem constants
#define S_    32
#define U_    10
#define B_    320           // S*U sequences
#define T_    120
#define NMEL_ 40
#define H_    768
#define G4_   3072          // 4*H gates
#define D_    256
#define XP_   64            // mel features zero-padded 40 -> 64 (multiple of 32)
#define K0_   (XP_ + H_)    // 832, layer-0 fused K
#define K12_  (2 * H_)      // 1536, layers 1/2 fused K

#define NB0   48            // layer-0 blocks (16 units each)
#define NB12  96            // layer-1/2 blocks (8 units each)
#define NBLK  (NB0 + 2 * NB12)  // 240 total, 1 block/CU (LDS-bound)

#define PITCH0  (K0_ + 8)   // LDS row pitch in halfs
#define PITCH12 (K12_ + 8)
#define SMEM_BYTES (64 * PITCH0 * 2)   // 107,520 B (layer-0 blocks are largest)

typedef _Float16 half8 __attribute__((ext_vector_type(8)));
typedef float floatx4 __attribute__((ext_vector_type(4)));

__device__ __forceinline__ float sigm(float x) {
  return 1.f / (1.f + __expf(-x));
}
__device__ __forceinline__ float tanh_f(float x) {
  x = fminf(15.f, fmaxf(-15.f, x));
  float e = __expf(2.f * x);
  return (e - 1.f) / (e + 1.f);
}

// ---------------- prep kernels ----------------

__global__ void prep_x0(const float* __restrict__ mel, _Float16* __restrict__ x0) {
  int idx = blockIdx.x * 256 + threadIdx.x;
  if (idx >= B_ * T_ * XP_) return;
  int k = idx & (XP_ - 1);
  int t = (idx >> 6) % T_;
  int b = idx / (XP_ * T_);
  float v = (k < NMEL_) ? mel[((size_t)b * NMEL_ + k) * T_ + t] : 0.f;
  x0[idx] = (_Float16)v;
}

__global__ void prep_w0(const float* __restrict__ Wih, const float* __restrict__ Whh,
                        _Float16* __restrict__ Wc) {
  int idx = blockIdx.x * 256 + threadIdx.x;
  if (idx >= G4_ * K0_) return;
  int k = idx % K0_;
  int n = idx / K0_;
  float v = 0.f;
  if (k < NMEL_)      v = Wih[(size_t)n * NMEL_ + k];
  else if (k >= XP_)  v = Whh[(size_t)n * H_ + (k - XP_)];
  Wc[idx] = (_Float16)v;
}

__global__ void prep_w12(const float* __restrict__ Wih, const float* __restrict__ Whh,
                         _Float16* __restrict__ Wc) {
  int idx = blockIdx.x * 256 + threadIdx.x;
  if (idx >= G4_ * K12_) return;
  int k = idx % K12_;
  int n = idx / K12_;
  float v = (k < H_) ? Wih[(size_t)n * H_ + k] : Whh[(size_t)n * H_ + (k - H_)];
  Wc[idx] = (_Float16)v;
}

__global__ void prep_bias(const float* __restrict__ bih, const float* __restrict__ bhh,
                          float* __restrict__ bias) {
  int idx = blockIdx.x * 256 + threadIdx.x;
  if (idx < G4_) bias[idx] = bih[idx] + bhh[idx];
}

// ---------------- persistent LSTM (weights LDS-resident) ----------------

__device__ __forceinline__ void wait_flag(int* flags, int sp, int lp) {
  if (lp < 0 || lp > 2) return;
  if (sp < lp || sp > lp + T_ - 1) return;       // layer lp not scheduled at step sp
  const int tgt = (lp == 0) ? NB0 : NB12;
  int spin = 0;
  while (__hip_atomic_load(&flags[sp * 3 + lp], __ATOMIC_RELAXED,
                           __HIP_MEMORY_SCOPE_AGENT) < tgt) {
    __builtin_amdgcn_s_sleep(2);
    if (++spin > 2000000) break;                 // bounded: fail as absmax, not hang
  }
}

// Deep-pipelined GEMM over K-chunks of 32. PF chunks in flight (circular regs),
// fully unrolled so slot indices are compile-time constants.
template <int NT, int PF, int NC>
__device__ __forceinline__ void gemm_pipe(
    const _Float16* __restrict__ lw, int pitch, int xK,
    const _Float16* __restrict__ xsrc, size_t xstr, const _Float16* __restrict__ hown,
    int m0, int m1, int lr, int quad, floatx4 (&acc)[2][NT]) {
  const int ko = quad * 8;

  half8 af[PF][2];
  half8 bf[PF][NT];

  auto aload = [&](int c, int slot) {
    const int kc = c * 32;
    const bool inx = kc < xK;
    const _Float16* base = inx ? (xsrc + kc + ko) : (hown + (kc - xK) + ko);
    const size_t str = inx ? xstr : (size_t)H_;
    af[slot][0] = *(const half8*)(base + (size_t)(m0 + lr) * str);
    af[slot][1] = *(const half8*)(base + (size_t)(m1 + lr) * str);
  };
  auto bload = [&](int c, int slot) {
    const int kc = c * 32;
#pragma unroll
    for (int nt = 0; nt < NT; ++nt)
      bf[slot][nt] = *(const half8*)(lw + (size_t)(nt * 16 + lr) * pitch + kc + ko);
  };

#pragma unroll
  for (int p = 0; p < PF - 1; ++p) { aload(p, p); bload(p, p); }

#pragma unroll
  for (int c = 0; c < NC; ++c) {
    const int slot = c % PF;
    const int pc = c + PF - 1;
    if (pc < NC) { aload(pc, pc % PF); bload(pc, pc % PF); }
#pragma unroll
    for (int nt = 0; nt < NT; ++nt) {
      acc[0][nt] = __builtin_amdgcn_mfma_f32_16x16x32_f16(af[slot][0], bf[slot][nt],
                                                          acc[0][nt], 0, 0, 0);
      acc[1][nt] = __builtin_amdgcn_mfma_f32_16x16x32_f16(af[slot][1], bf[slot][nt],
                                                          acc[1][nt], 0, 0, 0);
    }
  }
}

__global__ __launch_bounds__(640)
void lstm_persist(const _Float16* __restrict__ x0,
                  const _Float16* __restrict__ Wc0, const _Float16* __restrict__ Wc1,
                  const _Float16* __restrict__ Wc2,
                  const float* __restrict__ bias, _Float16* __restrict__ hbuf,
                  int* __restrict__ flags) {
  extern __shared__ _Float16 lw[];
  const int bid = blockIdx.x;

  int layer, tile, units, K, pitch;
  const _Float16* Wsrc;
  if (bid < NB0)            { layer = 0; tile = bid;              units = 16; K = K0_;  pitch = PITCH0;  Wsrc = Wc0; }
  else if (bid < NB0+NB12)  { layer = 1; tile = bid - NB0;        units = 8;  K = K12_; pitch = PITCH12; Wsrc = Wc1; }
  else                      { layer = 2; tile = bid - NB0 - NB12; units = 8;  K = K12_; pitch = PITCH12; Wsrc = Wc2; }
  const int nrows = units * 4;
  const int j0 = tile * units;

  // ---- one-time: stage this block's weight slice into LDS ----
  {
    const int nchunks = K / 8;
    for (int idx = threadIdx.x; idx < nrows * nchunks; idx += 640) {
      int r = idx / nchunks;
      int k8 = (idx % nchunks) * 8;
      int grow = (r / units) * H_ + j0 + (r % units);   // gate-major rows
      half8 v = *(const half8*)(Wsrc + (size_t)grow * K + k8);
      *(half8*)(lw + (size_t)r * pitch + k8) = v;
    }
  }
  __syncthreads();

  const int lane = threadIdx.x & 63;
  const int wv = threadIdx.x >> 6;      // 10 waves
  const int lr = lane & 15;
  const int quad = lane >> 4;
  const int m0 = wv * 32;
  const int m1 = wv * 32 + 16;
  const int j = j0 + ((units == 16) ? lr : (lr & 7));

  const float bI = bias[layer * G4_ + 0 * H_ + j];
  const float bF = bias[layer * G4_ + 1 * H_ + j];
  const float bG = bias[layer * G4_ + 2 * H_ + j];
  const float bO = bias[layer * G4_ + 3 * H_ + j];

  float cst[2][4] = {{0.f, 0.f, 0.f, 0.f}, {0.f, 0.f, 0.f, 0.f}};

  for (int t = 0; t < T_; ++t) {
    const int s = layer + t;

    // ---- producer waits (true deps): (l-1, s-1) for x-part, (l, s-1) for own-h ----
    if (threadIdx.x == 0) {
      wait_flag(flags, s - 1, layer - 1);
      wait_flag(flags, s - 1, layer);
      __builtin_amdgcn_fence(__ATOMIC_ACQUIRE, "agent");   // one L1/L2 inv, not per-poll
    }
    __syncthreads();

    const int pprev = (s - 1) & 1;
    const int pcur = s & 1;
    const _Float16* xsrc;
    size_t xstr;
    if (layer == 0) { xsrc = x0 + (size_t)t * XP_; xstr = (size_t)T_ * XP_; }
    else { xsrc = hbuf + (size_t)((layer - 1) * 2 + pprev) * B_ * H_; xstr = H_; }
    const _Float16* hown = hbuf + (size_t)(layer * 2 + pprev) * B_ * H_;
    _Float16* hout = hbuf + (size_t)(layer * 2 + pcur) * B_ * H_;

    floatx4 acc0[2][4];
    floatx4 acc2[2][2];
    if (layer == 0) {
#pragma unroll
      for (int a = 0; a < 2; ++a)
#pragma unroll
        for (int b = 0; b < 4; ++b) acc0[a][b] = (floatx4){0.f, 0.f, 0.f, 0.f};
      gemm_pipe<4, 3, K0_ / 32>(lw, PITCH0, XP_, xsrc, xstr, hown, m0, m1, lr, quad, acc0);
    } else {
#pragma unroll
      for (int a = 0; a < 2; ++a)
#pragma unroll
        for (int b = 0; b < 2; ++b) acc2[a][b] = (floatx4){0.f, 0.f, 0.f, 0.f};
      gemm_pipe<2, 4, K12_ / 32>(lw, PITCH12, H_, xsrc, xstr, hown, m0, m1, lr, quad, acc2);
    }

    // ---- anti-dep wait (consumer of s-2 data must be done), hidden behind GEMM ----
    if (threadIdx.x == 0) {
      wait_flag(flags, s - 1, layer + 1);
      __builtin_amdgcn_fence(__ATOMIC_ACQUIRE, "agent");
    }
    __syncthreads();

    if (layer == 0) {
#pragma unroll
      for (int mt = 0; mt < 2; ++mt)
#pragma unroll
        for (int r = 0; r < 4; ++r) {
          float iv = acc0[mt][0][r] + bI;
          float fv = acc0[mt][1][r] + bF;
          float gv = acc0[mt][2][r] + bG;
          float ov = acc0[mt][3][r] + bO;
          float cn = sigm(fv) * cst[mt][r] + sigm(iv) * tanh_f(gv);
          cst[mt][r] = cn;
          int m = (mt ? m1 : m0) + quad * 4 + r;
          hout[(size_t)m * H_ + j] = (_Float16)(sigm(ov) * tanh_f(cn));
        }
    } else {
      // tile0 cols: i(units 0..7), f(units 0..7); tile1: g, o. xor-8 colocates gates.
#pragma unroll
      for (int mt = 0; mt < 2; ++mt)
#pragma unroll
        for (int r = 0; r < 4; ++r) {
          float t0 = acc2[mt][0][r], t1 = acc2[mt][1][r];
          float p0 = __shfl_xor(t0, 8, 64);
          float p1 = __shfl_xor(t1, 8, 64);
          bool lo = (lr < 8);
          float iv = (lo ? t0 : p0) + bI;
          float fv = (lo ? p0 : t0) + bF;
          float gv = (lo ? t1 : p1) + bG;
          float ov = (lo ? p1 : t1) + bO;
          float cn = sigm(fv) * cst[mt][r] + sigm(iv) * tanh_f(gv);
          cst[mt][r] = cn;
          if (lo) {
            int m = (mt ? m1 : m0) + quad * 4 + r;
            hout[(size_t)m * H_ + j] = (_Float16)(sigm(ov) * tanh_f(cn));
          }
        }
    }

    // ---- publish: barrier drains all waves' stores, release-add writes back L2 ----
    __syncthreads();
    if (threadIdx.x == 0)
      __hip_atomic_fetch_add(&flags[s * 3 + layer], 1, __ATOMIC_RELEASE,
                             __HIP_MEMORY_SCOPE_AGENT);
  }
}

// ---------------- projection + normalize ----------------
__global__ void dvec_kernel(const _Float16* __restrict__ hlast, const float* __restrict__ Wproj,
                            const float* __restrict__ bproj, float* __restrict__ d3) {
  const int m = blockIdx.x;
  const int d = threadIdx.x;
  const _Float16* h = hlast + (size_t)m * H_;
  const float* w = Wproj + (size_t)d * H_;
  float acc = bproj[d];
  for (int k = 0; k < H_; k++) acc += (float)h[k] * w[k];
  __shared__ float red[256];
  red[d] = acc * acc;
  __syncthreads();
  for (int off = 128; off > 0; off >>= 1) {
    if (d < off) red[d] += red[d + off];
    __syncthreads();
  }
  float nrm = sqrtf(red[0]);
  d3[(size_t)m * D_ + d] = acc / nrm;
}

// ---------------- GE2E ----------------
__device__ float block_reduce_sum(float x, float* red) {
  const int d = threadIdx.x;
  red[d] = x;
  __syncthreads();
  for (int off = 128; off > 0; off >>= 1) {
    if (d < off) red[d] += red[d + off];
    __syncthreads();
  }
  float r = red[0];
  __syncthreads();
  return r;
}

__global__ void cent_kernel(const float* __restrict__ d3, float* __restrict__ cent,
                            float* __restrict__ ncent) {
  const int sIdx = blockIdx.x;
  const int d = threadIdx.x;
  float acc = 0.f;
  for (int u = 0; u < U_; u++) acc += d3[((size_t)sIdx * U_ + u) * D_ + d];
  acc *= (1.f / U_);
  cent[sIdx * D_ + d] = acc;
  __shared__ float red[256];
  float n2 = block_reduce_sum(acc * acc, red);
  if (d == 0) ncent[sIdx] = fmaxf(sqrtf(n2), 1e-8f);
}

__global__ void ge2e_kernel(const float* __restrict__ d3, const float* __restrict__ cent,
                            const float* __restrict__ ncent, const float* __restrict__ loss_w,
                            const float* __restrict__ loss_b, float* __restrict__ accums) {
  const int p = blockIdx.x;      // (s,u) pair
  const int sIdx = p / U_;
  const int d = threadIdx.x;
  __shared__ float red[256];
  __shared__ float sims[S_];

  const float v = d3[(size_t)p * D_ + d];
  const float cs = cent[sIdx * D_ + d];
  const float pc = (cs * U_ - v) * (1.f / (U_ - 1));

  float nv2 = block_reduce_sum(v * v, red);
  float npc2 = block_reduce_sum(pc * pc, red);
  float dotp = block_reduce_sum(v * pc, red);

  const float w = loss_w[0], b = loss_b[0];
  const float na = fmaxf(sqrtf(nv2), 1e-6f);
  const float npc = fmaxf(sqrtf(npc2), 1e-6f);
  const float pos_sim = w * (dotp / (na * npc)) + b;
  const float nd = fmaxf(sqrtf(nv2), 1e-8f);

  for (int k = 0; k < S_; k++) {
    float dk = block_reduce_sum(v * cent[k * D_ + d], red);
    if (d == 0) sims[k] = w * (dk / (nd * ncent[k])) + b;
  }
  __syncthreads();
  if (d == 0) {
    float mx = -1e30f;
    for (int k = 0; k < S_; k++)
      if (k != sIdx) mx = fmaxf(mx, sims[k]);
    float se = 0.f, sn = 0.f;
    for (int k = 0; k < S_; k++)
      if (k != sIdx) { se += expf(sims[k] - mx); sn += sims[k]; }
    float lse = mx + logf(se);
    atomicAdd(&accums[0], -pos_sim + lse);
    atomicAdd(&accums[1], pos_sim);
    atomicAdd(&accums[2], sn);
  }
}

__global__ void finalize_kernel(const float* __restrict__ accums, float* __restrict__ out) {
  if (threadIdx.x == 0) {
    out[0] = accums[0] / (float)(S_ * U_);
    out[1] = accums[1] / (float)(S_ * U_);
    out[2] = accums[2] / (float)(S_ * U_ * (S_ - 1));
  }
}

// ---------------- launch ----------------
extern "C" void kernel_launch(void* const* d_in, const int* in_sizes, int n_in,
                              void* d_out, int out_size, void* d_ws, size_t ws_size,
                              hipStream_t stream) {
  const float* mel = (const float*)d_in[0];
  const float* Wih[3] = {(const float*)d_in[1], (const float*)d_in[5], (const float*)d_in[9]};
  const float* Whh[3] = {(const float*)d_in[2], (const float*)d_in[6], (const float*)d_in[10]};
  const float* bih[3] = {(const float*)d_in[3], (const float*)d_in[7], (const float*)d_in[11]};
  const float* bhh[3] = {(const float*)d_in[4], (const float*)d_in[8], (const float*)d_in[12]};
  const float* Wproj = (const float*)d_in[13];
  const float* bproj = (const float*)d_in[14];
  const float* loss_w = (const float*)d_in[15];
  const float* loss_b = (const float*)d_in[16];
  float* out = (float*)d_out;

  char* ws = (char*)d_ws;
  size_t off = 0;
  auto alloc = [&](size_t bytes) -> void* {
    void* p = ws + off;
    off = (off + bytes + 255) & ~(size_t)255;
    return p;
  };
  _Float16* x0   = (_Float16*)alloc((size_t)B_ * T_ * XP_ * 2);
  _Float16* Wc0  = (_Float16*)alloc((size_t)G4_ * K0_ * 2);
  _Float16* Wc1  = (_Float16*)alloc((size_t)G4_ * K12_ * 2);
  _Float16* Wc2  = (_Float16*)alloc((size_t)G4_ * K12_ * 2);
  float*    bias = (float*)alloc((size_t)3 * G4_ * 4);
  _Float16* hbuf = (_Float16*)alloc((size_t)6 * B_ * H_ * 2);
  float*    d3   = (float*)alloc((size_t)B_ * D_ * 4);
  float*    cent = (float*)alloc((size_t)S_ * D_ * 4);
  float*    ncent = (float*)alloc((size_t)S_ * 4);
  float*    accums = (float*)alloc(64);
  int*      flags = (int*)alloc((size_t)(T_ + 3) * 3 * 4);

  hipMemsetAsync(hbuf, 0, (size_t)6 * B_ * H_ * 2, stream);
  hipMemsetAsync(accums, 0, 64, stream);
  hipMemsetAsync(flags, 0, (size_t)(T_ + 3) * 3 * 4, stream);

  prep_x0<<<(B_ * T_ * XP_ + 255) / 256, 256, 0, stream>>>(mel, x0);
  prep_w0<<<(G4_ * K0_ + 255) / 256, 256, 0, stream>>>(Wih[0], Whh[0], Wc0);
  prep_w12<<<(G4_ * K12_ + 255) / 256, 256, 0, stream>>>(Wih[1], Whh[1], Wc1);
  prep_w12<<<(G4_ * K12_ + 255) / 256, 256, 0, stream>>>(Wih[2], Whh[2], Wc2);
  for (int l = 0; l < 3; l++)
    prep_bias<<<(G4_ + 255) / 256, 256, 0, stream>>>(bih[l], bhh[l], bias + l * G4_);

  hipFuncSetAttribute((const void*)lstm_persist,
                      hipFuncAttributeMaxDynamicSharedMemorySize, SMEM_BYTES);
  void* kargs[] = {(void*)&x0, (void*)&Wc0, (void*)&Wc1, (void*)&Wc2,
                   (void*)&bias, (void*)&hbuf, (void*)&flags};
  hipLaunchCooperativeKernel((const void*)lstm_persist, dim3(NBLK), dim3(640),
                             kargs, SMEM_BYTES, stream);

  const _Float16* hlast = hbuf + (size_t)(2 * 2 + 1) * B_ * H_;
  dvec_kernel<<<B_, 256, 0, stream>>>(hlast, Wproj, bproj, d3);
  cent_kernel<<<S_, 256, 0, stream>>>(d3, cent, ncent);
  ge2e_kernel<<<B_, 256, 0, stream>>>(d3, cent, ncent, loss_w, loss_b, accums);
  finalize_kernel<<<1, 64, 0, stream>>>(accums, out);
}

// Round 4
// 5947.693 us; speedup vs baseline: 1.0181x; 1.0181x over previous
//
#include <hip/hip_runtime.h>
#include <math.h>

// Problem constants
#define S_    32
#define U_    10
#define B_    320           // S*U sequences
#define T_    120
#define NMEL_ 40
#define H_    768
#define G4_   3072          // 4*H gates
#define D_    256
#define XP_   64            // mel features zero-padded 40 -> 64 (multiple of 32)
#define K0_   (XP_ + H_)    // 832, layer-0 fused K
#define K12_  (2 * H_)      // 1536, layers 1/2 fused K

#define NB0   48            // layer-0 blocks (16 units each)
#define NB12  96            // layer-1/2 blocks (8 units each)
#define NBLK  (NB0 + 2 * NB12)  // 240 total, 1 block/CU (LDS-bound)

// LDS: chunk-major swizzle [(c*nrows + r)*32 + k] -> ds_read_b128 is 1024B contiguous
#define SMEM_BYTES (26 * 64 * 32 * 2)   // layer-0: 26 chunks x 64 rows x 32 halfs = 106,496 B

typedef _Float16 half8 __attribute__((ext_vector_type(8)));
typedef float floatx4 __attribute__((ext_vector_type(4)));

__device__ __forceinline__ float sigm(float x) {
  return 1.f / (1.f + __expf(-x));
}
__device__ __forceinline__ float tanh_f(float x) {
  x = fminf(15.f, fmaxf(-15.f, x));
  float e = __expf(2.f * x);
  return (e - 1.f) / (e + 1.f);
}

// ---------------- prep kernels ----------------

__global__ void prep_x0(const float* __restrict__ mel, _Float16* __restrict__ x0) {
  int idx = blockIdx.x * 256 + threadIdx.x;
  if (idx >= B_ * T_ * XP_) return;
  int k = idx & (XP_ - 1);
  int t = (idx >> 6) % T_;
  int b = idx / (XP_ * T_);
  float v = (k < NMEL_) ? mel[((size_t)b * NMEL_ + k) * T_ + t] : 0.f;
  x0[idx] = (_Float16)v;
}

__global__ void prep_w0(const float* __restrict__ Wih, const float* __restrict__ Whh,
                        _Float16* __restrict__ Wc) {
  int idx = blockIdx.x * 256 + threadIdx.x;
  if (idx >= G4_ * K0_) return;
  int k = idx % K0_;
  int n = idx / K0_;
  float v = 0.f;
  if (k < NMEL_)      v = Wih[(size_t)n * NMEL_ + k];
  else if (k >= XP_)  v = Whh[(size_t)n * H_ + (k - XP_)];
  Wc[idx] = (_Float16)v;
}

__global__ void prep_w12(const float* __restrict__ Wih, const float* __restrict__ Whh,
                         _Float16* __restrict__ Wc) {
  int idx = blockIdx.x * 256 + threadIdx.x;
  if (idx >= G4_ * K12_) return;
  int k = idx % K12_;
  int n = idx / K12_;
  float v = (k < H_) ? Wih[(size_t)n * H_ + k] : Whh[(size_t)n * H_ + (k - H_)];
  Wc[idx] = (_Float16)v;
}

__global__ void prep_bias(const float* __restrict__ bih, const float* __restrict__ bhh,
                          float* __restrict__ bias) {
  int idx = blockIdx.x * 256 + threadIdx.x;
  if (idx < G4_) bias[idx] = bih[idx] + bhh[idx];
}

// ---------------- persistent LSTM (weights LDS-resident) ----------------

__device__ __forceinline__ void wait_flag(int* flags, int sp, int lp) {
  if (lp < 0 || lp > 2) return;
  if (sp < lp || sp > lp + T_ - 1) return;       // layer lp not scheduled at step sp
  const int tgt = (lp == 0) ? NB0 : NB12;
  int spin = 0;
  while (__hip_atomic_load(&flags[sp * 3 + lp], __ATOMIC_RELAXED,
                           __HIP_MEMORY_SCOPE_AGENT) < tgt) {
    __builtin_amdgcn_s_sleep(2);
    if (++spin > 2000000) break;                 // bounded: fail as absmax, not hang
  }
}

// Deep-pipelined GEMM over K-chunks of 32. PF chunks in flight (circular regs),
// fully unrolled so slot indices are compile-time constants. XKC = chunks of x-input.
template <int NT, int PF, int NC, int XKC>
__device__ __forceinline__ void gemm_pipe(
    const _Float16* __restrict__ lw,
    const _Float16* __restrict__ xsrc, size_t xstr, const _Float16* __restrict__ hown,
    int m0, int m1, int lr, int quad, floatx4 (&acc)[2][NT]) {
  const int ko = quad * 8;
  const int nrows = NT * 16;

  half8 af[PF][2];
  half8 bf[PF][NT];

  auto aload = [&](int c, int slot) {
    const int kc = c * 32;
    const bool inx = c < XKC;
    const _Float16* base = inx ? (xsrc + kc + ko) : (hown + (kc - XKC * 32) + ko);
    const size_t str = inx ? xstr : (size_t)H_;
    af[slot][0] = *(const half8*)(base + (size_t)(m0 + lr) * str);
    af[slot][1] = *(const half8*)(base + (size_t)(m1 + lr) * str);
  };
  auto bload = [&](int c, int slot) {
#pragma unroll
    for (int nt = 0; nt < NT; ++nt)
      bf[slot][nt] = *(const half8*)(lw + ((size_t)(c * nrows + nt * 16 + lr) * 32 + ko));
  };

#pragma unroll
  for (int p = 0; p < PF - 1; ++p) { aload(p, p); bload(p, p); }

#pragma unroll
  for (int c = 0; c < NC; ++c) {
    const int slot = c % PF;
    const int pc = c + PF - 1;
    if (pc < NC) { aload(pc, pc % PF); bload(pc, pc % PF); }
#pragma unroll
    for (int nt = 0; nt < NT; ++nt) {
      acc[0][nt] = __builtin_amdgcn_mfma_f32_16x16x32_f16(af[slot][0], bf[slot][nt],
                                                          acc[0][nt], 0, 0, 0);
      acc[1][nt] = __builtin_amdgcn_mfma_f32_16x16x32_f16(af[slot][1], bf[slot][nt],
                                                          acc[1][nt], 0, 0, 0);
    }
  }
}

__global__ __launch_bounds__(640, 3)   // 3 waves/EU min -> VGPR budget ~170, keeps pipeline live
void lstm_persist(const _Float16* __restrict__ x0,
                  const _Float16* __restrict__ Wc0, const _Float16* __restrict__ Wc1,
                  const _Float16* __restrict__ Wc2,
                  const float* __restrict__ bias, _Float16* __restrict__ hbuf,
                  int* __restrict__ flags) {
  extern __shared__ _Float16 lw[];
  const int bid = blockIdx.x;

  int layer, tile, units, K;
  const _Float16* Wsrc;
  if (bid < NB0)            { layer = 0; tile = bid;              units = 16; K = K0_;  Wsrc = Wc0; }
  else if (bid < NB0+NB12)  { layer = 1; tile = bid - NB0;        units = 8;  K = K12_; Wsrc = Wc1; }
  else                      { layer = 2; tile = bid - NB0 - NB12; units = 8;  K = K12_; Wsrc = Wc2; }
  const int nrows = units * 4;
  const int j0 = tile * units;

  // ---- one-time: stage weight slice into LDS, chunk-major swizzled layout ----
  {
    const int total = (K / 32) * nrows * 4;     // half8 units
    for (int idx = threadIdx.x; idx < total; idx += 640) {
      int c = idx / (nrows * 4);
      int rem = idx % (nrows * 4);
      int r = rem >> 2;
      int q = rem & 3;
      int grow = (r / units) * H_ + j0 + (r % units);   // gate-major rows
      half8 v = *(const half8*)(Wsrc + (size_t)grow * K + c * 32 + q * 8);
      *(half8*)(lw + ((size_t)(c * nrows + r) * 32 + q * 8)) = v;
    }
  }
  __syncthreads();

  const int lane = threadIdx.x & 63;
  const int wv = threadIdx.x >> 6;      // 10 waves
  const int lr = lane & 15;
  const int quad = lane >> 4;
  const int m0 = wv * 32;
  const int m1 = wv * 32 + 16;
  const int j = j0 + ((units == 16) ? lr : (lr & 7));

  const float bI = bias[layer * G4_ + 0 * H_ + j];
  const float bF = bias[layer * G4_ + 1 * H_ + j];
  const float bG = bias[layer * G4_ + 2 * H_ + j];
  const float bO = bias[layer * G4_ + 3 * H_ + j];

  float cst[2][4] = {{0.f, 0.f, 0.f, 0.f}, {0.f, 0.f, 0.f, 0.f}};

  for (int t = 0; t < T_; ++t) {
    const int s = layer + t;

    // ---- producer waits (true deps): (l-1, s-1) for x-part, (l, s-1) for own-h
    //      (l, s-1) also covers the same-layer anti-dep on buffer (l, pcur).
    if (threadIdx.x == 0) {
      wait_flag(flags, s - 1, layer - 1);
      wait_flag(flags, s - 1, layer);
      __builtin_amdgcn_fence(__ATOMIC_ACQUIRE, "agent");   // one cache-inv per step
    }
    __syncthreads();

    const int pprev = (s - 1) & 1;
    const int pcur = s & 1;
    const _Float16* xsrc;
    size_t xstr;
    if (layer == 0) { xsrc = x0 + (size_t)t * XP_; xstr = (size_t)T_ * XP_; }
    else { xsrc = hbuf + (size_t)((layer - 1) * 2 + pprev) * B_ * H_; xstr = H_; }
    const _Float16* hown = hbuf + (size_t)(layer * 2 + pprev) * B_ * H_;
    _Float16* hout = hbuf + (size_t)(layer * 2 + pcur) * B_ * H_;

    floatx4 acc0[2][4];
    floatx4 acc2[2][2];
    if (layer == 0) {
#pragma unroll
      for (int a = 0; a < 2; ++a)
#pragma unroll
        for (int b = 0; b < 4; ++b) acc0[a][b] = (floatx4){0.f, 0.f, 0.f, 0.f};
      gemm_pipe<4, 3, K0_ / 32, XP_ / 32>(lw, xsrc, xstr, hown, m0, m1, lr, quad, acc0);
    } else {
#pragma unroll
      for (int a = 0; a < 2; ++a)
#pragma unroll
        for (int b = 0; b < 2; ++b) acc2[a][b] = (floatx4){0.f, 0.f, 0.f, 0.f};
      gemm_pipe<2, 5, K12_ / 32, H_ / 32>(lw, xsrc, xstr, hown, m0, m1, lr, quad, acc2);
    }

    // ---- anti-dep wait (cross-layer consumer of buffer (l,pcur) must be done
    //      reading), hidden behind GEMM. Barrier ordering suffices; no fence.
    if (threadIdx.x == 0) wait_flag(flags, s - 1, layer + 1);
    __syncthreads();

    if (layer == 0) {
#pragma unroll
      for (int mt = 0; mt < 2; ++mt)
#pragma unroll
        for (int r = 0; r < 4; ++r) {
          float iv = acc0[mt][0][r] + bI;
          float fv = acc0[mt][1][r] + bF;
          float gv = acc0[mt][2][r] + bG;
          float ov = acc0[mt][3][r] + bO;
          float cn = sigm(fv) * cst[mt][r] + sigm(iv) * tanh_f(gv);
          cst[mt][r] = cn;
          int m = (mt ? m1 : m0) + quad * 4 + r;
          hout[(size_t)m * H_ + j] = (_Float16)(sigm(ov) * tanh_f(cn));
        }
    } else {
      // tile0 cols: i(units 0..7), f(units 0..7); tile1: g, o. xor-8 colocates gates.
#pragma unroll
      for (int mt = 0; mt < 2; ++mt)
#pragma unroll
        for (int r = 0; r < 4; ++r) {
          float t0 = acc2[mt][0][r], t1 = acc2[mt][1][r];
          float p0 = __shfl_xor(t0, 8, 64);
          float p1 = __shfl_xor(t1, 8, 64);
          bool lo = (lr < 8);
          float iv = (lo ? t0 : p0) + bI;
          float fv = (lo ? p0 : t0) + bF;
          float gv = (lo ? t1 : p1) + bG;
          float ov = (lo ? p1 : t1) + bO;
          float cn = sigm(fv) * cst[mt][r] + sigm(iv) * tanh_f(gv);
          cst[mt][r] = cn;
          if (lo) {
            int m = (mt ? m1 : m0) + quad * 4 + r;
            hout[(size_t)m * H_ + j] = (_Float16)(sigm(ov) * tanh_f(cn));
          }
        }
    }

    // ---- publish: barrier drains all waves' stores (vmcnt(0)), release writes back L2
    __syncthreads();
    if (threadIdx.x == 0)
      __hip_atomic_fetch_add(&flags[s * 3 + layer], 1, __ATOMIC_RELEASE,
                             __HIP_MEMORY_SCOPE_AGENT);
  }
}

// ---------------- projection + normalize ----------------
__global__ void dvec_kernel(const _Float16* __restrict__ hlast, const float* __restrict__ Wproj,
                            const float* __restrict__ bproj, float* __restrict__ d3) {
  const int m = blockIdx.x;
  const int d = threadIdx.x;
  const _Float16* h = hlast + (size_t)m * H_;
  const float* w = Wproj + (size_t)d * H_;
  float acc = bproj[d];
  for (int k = 0; k < H_; k++) acc += (float)h[k] * w[k];
  __shared__ float red[256];
  red[d] = acc * acc;
  __syncthreads();
  for (int off = 128; off > 0; off >>= 1) {
    if (d < off) red[d] += red[d + off];
    __syncthreads();
  }
  float nrm = sqrtf(red[0]);
  d3[(size_t)m * D_ + d] = acc / nrm;
}

// ---------------- GE2E ----------------
__device__ float block_reduce_sum(float x, float* red) {
  const int d = threadIdx.x;
  red[d] = x;
  __syncthreads();
  for (int off = 128; off > 0; off >>= 1) {
    if (d < off) red[d] += red[d + off];
    __syncthreads();
  }
  float r = red[0];
  __syncthreads();
  return r;
}

__global__ void cent_kernel(const float* __restrict__ d3, float* __restrict__ cent,
                            float* __restrict__ ncent) {
  const int sIdx = blockIdx.x;
  const int d = threadIdx.x;
  float acc = 0.f;
  for (int u = 0; u < U_; u++) acc += d3[((size_t)sIdx * U_ + u) * D_ + d];
  acc *= (1.f / U_);
  cent[sIdx * D_ + d] = acc;
  __shared__ float red[256];
  float n2 = block_reduce_sum(acc * acc, red);
  if (d == 0) ncent[sIdx] = fmaxf(sqrtf(n2), 1e-8f);
}

__global__ void ge2e_kernel(const float* __restrict__ d3, const float* __restrict__ cent,
                            const float* __restrict__ ncent, const float* __restrict__ loss_w,
                            const float* __restrict__ loss_b, float* __restrict__ accums) {
  const int p = blockIdx.x;      // (s,u) pair
  const int sIdx = p / U_;
  const int d = threadIdx.x;
  __shared__ float red[256];
  __shared__ float sims[S_];

  const float v = d3[(size_t)p * D_ + d];
  const float cs = cent[sIdx * D_ + d];
  const float pc = (cs * U_ - v) * (1.f / (U_ - 1));

  float nv2 = block_reduce_sum(v * v, red);
  float npc2 = block_reduce_sum(pc * pc, red);
  float dotp = block_reduce_sum(v * pc, red);

  const float w = loss_w[0], b = loss_b[0];
  const float na = fmaxf(sqrtf(nv2), 1e-6f);
  const float npc = fmaxf(sqrtf(npc2), 1e-6f);
  const float pos_sim = w * (dotp / (na * npc)) + b;
  const float nd = fmaxf(sqrtf(nv2), 1e-8f);

  for (int k = 0; k < S_; k++) {
    float dk = block_reduce_sum(v * cent[k * D_ + d], red);
    if (d == 0) sims[k] = w * (dk / (nd * ncent[k])) + b;
  }
  __syncthreads();
  if (d == 0) {
    float mx = -1e30f;
    for (int k = 0; k < S_; k++)
      if (k != sIdx) mx = fmaxf(mx, sims[k]);
    float se = 0.f, sn = 0.f;
    for (int k = 0; k < S_; k++)
      if (k != sIdx) { se += expf(sims[k] - mx); sn += sims[k]; }
    float lse = mx + logf(se);
    atomicAdd(&accums[0], -pos_sim + lse);
    atomicAdd(&accums[1], pos_sim);
    atomicAdd(&accums[2], sn);
  }
}

__global__ void finalize_kernel(const float* __restrict__ accums, float* __restrict__ out) {
  if (threadIdx.x == 0) {
    out[0] = accums[0] / (float)(S_ * U_);
    out[1] = accums[1] / (float)(S_ * U_);
    out[2] = accums[2] / (float)(S_ * U_ * (S_ - 1));
  }
}

// ---------------- launch ----------------
extern "C" void kernel_launch(void* const* d_in, const int* in_sizes, int n_in,
                              void* d_out, int out_size, void* d_ws, size_t ws_size,
                              hipStream_t stream) {
  const float* mel = (const float*)d_in[0];
  const float* Wih[3] = {(const float*)d_in[1], (const float*)d_in[5], (const float*)d_in[9]};
  const float* Whh[3] = {(const float*)d_in[2], (const float*)d_in[6], (const float*)d_in[10]};
  const float* bih[3] = {(const float*)d_in[3], (const float*)d_in[7], (const float*)d_in[11]};
  const float* bhh[3] = {(const float*)d_in[4], (const float*)d_in[8], (const float*)d_in[12]};
  const float* Wproj = (const float*)d_in[13];
  const float* bproj = (const float*)d_in[14];
  const float* loss_w = (const float*)d_in[15];
  const float* loss_b = (const float*)d_in[16];
  float* out = (float*)d_out;

  char* ws = (char*)d_ws;
  size_t off = 0;
  auto alloc = [&](size_t bytes) -> void* {
    void* p = ws + off;
    off = (off + bytes + 255) & ~(size_t)255;
    return p;
  };
  _Float16* x0   = (_Float16*)alloc((size_t)B_ * T_ * XP_ * 2);
  _Float16* Wc0  = (_Float16*)alloc((size_t)G4_ * K0_ * 2);
  _Float16* Wc1  = (_Float16*)alloc((size_t)G4_ * K12_ * 2);
  _Float16* Wc2  = (_Float16*)alloc((size_t)G4_ * K12_ * 2);
  float*    bias = (float*)alloc((size_t)3 * G4_ * 4);
  _Float16* hbuf = (_Float16*)alloc((size_t)6 * B_ * H_ * 2);
  float*    d3   = (float*)alloc((size_t)B_ * D_ * 4);
  float*    cent = (float*)alloc((size_t)S_ * D_ * 4);
  float*    ncent = (float*)alloc((size_t)S_ * 4);
  float*    accums = (float*)alloc(64);
  int*      flags = (int*)alloc((size_t)(T_ + 3) * 3 * 4);

  hipMemsetAsync(hbuf, 0, (size_t)6 * B_ * H_ * 2, stream);
  hipMemsetAsync(accums, 0, 64, stream);
  hipMemsetAsync(flags, 0, (size_t)(T_ + 3) * 3 * 4, stream);

  prep_x0<<<(B_ * T_ * XP_ + 255) / 256, 256, 0, stream>>>(mel, x0);
  prep_w0<<<(G4_ * K0_ + 255) / 256, 256, 0, stream>>>(Wih[0], Whh[0], Wc0);
  prep_w12<<<(G4_ * K12_ + 255) / 256, 256, 0, stream>>>(Wih[1], Whh[1], Wc1);
  prep_w12<<<(G4_ * K12_ + 255) / 256, 256, 0, stream>>>(Wih[2], Whh[2], Wc2);
  for (int l = 0; l < 3; l++)
    prep_bias<<<(G4_ + 255) / 256, 256, 0, stream>>>(bih[l], bhh[l], bias + l * G4_);

  hipFuncSetAttribute((const void*)lstm_persist,
                      hipFuncAttributeMaxDynamicSharedMemorySize, SMEM_BYTES);
  void* kargs[] = {(void*)&x0, (void*)&Wc0, (void*)&Wc1, (void*)&Wc2,
                   (void*)&bias, (void*)&hbuf, (void*)&flags};
  hipLaunchCooperativeKernel((const void*)lstm_persist, dim3(NBLK), dim3(640),
                             kargs, SMEM_BYTES, stream);

  const _Float16* hlast = hbuf + (size_t)(2 * 2 + 1) * B_ * H_;
  dvec_kernel<<<B_, 256, 0, stream>>>(hlast, Wproj, bproj, d3);
  cent_kernel<<<S_, 256, 0, stream>>>(d3, cent, ncent);
  ge2e_kernel<<<B_, 256, 0, stream>>>(d3, cent, ncent, loss_w, loss_b, accums);
  finalize_kernel<<<1, 64, 0, stream>>>(accums, out);
}

// Round 5
// 5133.136 us; speedup vs baseline: 1.1797x; 1.1587x over previous
//
#include <hip/hip_runtime.h>
#include <math.h>

// Problem constants
#define S_    32
#define U_    10
#define B_    320           // S*U sequences
#define T_    120
#define NMEL_ 40
#define H_    768
#define G4_   3072          // 4*H gates
#define D_    256
#define XP_   64            // mel features zero-padded 40 -> 64
#define K0_   (XP_ + H_)    // 832, layer-0 fused K
#define K12_  (2 * H_)      // 1536, layers 1/2 fused K

#define NB0   48            // layer-0 blocks (16 units each)
#define NB12  96            // layer-1/2 blocks (8 units each)
#define NBLK  (NB0 + 2 * NB12)  // 240 blocks, 1 per CU

// LDS: weights chunk-major [(c*nrows + r)*32 + k] (64 B rows), then A-stage ring.
// layers 1/2: 48*32*64 = 98,304 B weights + 3*20,480 ring = 159,744
// layer 0:    26*64*64 = 106,496 B weights + 2*20,480 ring = 147,456
#define SMEM_BYTES 159744

typedef _Float16 half8 __attribute__((ext_vector_type(8)));
typedef float floatx4 __attribute__((ext_vector_type(4)));

__device__ __forceinline__ float sigm(float x) {
  return 1.f / (1.f + __expf(-x));
}
__device__ __forceinline__ float tanh_f(float x) {
  x = fminf(15.f, fmaxf(-15.f, x));
  float e = __expf(2.f * x);
  return (e - 1.f) / (e + 1.f);
}

// async global->LDS DMA, 16 B per lane; LDS dest = wave-uniform base + lane*16
__device__ __forceinline__ void dma16(const void* g, void* l) {
  __builtin_amdgcn_global_load_lds(
      (const __attribute__((address_space(1))) unsigned int*)g,
      (__attribute__((address_space(3))) unsigned int*)l, 16, 0, 0);
}

// s_waitcnt vmcnt(N) only (expcnt/lgkmcnt fields all-ones = no wait).
// gfx9-family encoding: vmcnt[3:0] bits 3:0, vmcnt[5:4] bits 15:14.
template <int N>
__device__ __forceinline__ void waitvm() {
  __builtin_amdgcn_s_waitcnt(0x3FF0 | (N & 0xF) | ((N >> 4) << 14));
}

// ---------------- prep kernels ----------------

__global__ void prep_x0(const float* __restrict__ mel, _Float16* __restrict__ x0) {
  int idx = blockIdx.x * 256 + threadIdx.x;
  if (idx >= B_ * T_ * XP_) return;
  int k = idx & (XP_ - 1);
  int t = (idx >> 6) % T_;
  int b = idx / (XP_ * T_);
  float v = (k < NMEL_) ? mel[((size_t)b * NMEL_ + k) * T_ + t] : 0.f;
  x0[idx] = (_Float16)v;
}

__global__ void prep_w0(const float* __restrict__ Wih, const float* __restrict__ Whh,
                        _Float16* __restrict__ Wc) {
  int idx = blockIdx.x * 256 + threadIdx.x;
  if (idx >= G4_ * K0_) return;
  int k = idx % K0_;
  int n = idx / K0_;
  float v = 0.f;
  if (k < NMEL_)      v = Wih[(size_t)n * NMEL_ + k];
  else if (k >= XP_)  v = Whh[(size_t)n * H_ + (k - XP_)];
  Wc[idx] = (_Float16)v;
}

__global__ void prep_w12(const float* __restrict__ Wih, const float* __restrict__ Whh,
                         _Float16* __restrict__ Wc) {
  int idx = blockIdx.x * 256 + threadIdx.x;
  if (idx >= G4_ * K12_) return;
  int k = idx % K12_;
  int n = idx / K12_;
  float v = (k < H_) ? Wih[(size_t)n * H_ + k] : Whh[(size_t)n * H_ + (k - H_)];
  Wc[idx] = (_Float16)v;
}

__global__ void prep_bias(const float* __restrict__ bih, const float* __restrict__ bhh,
                          float* __restrict__ bias) {
  int idx = blockIdx.x * 256 + threadIdx.x;
  if (idx < G4_) bias[idx] = bih[idx] + bhh[idx];
}

// ---------------- persistent LSTM ----------------

__device__ __forceinline__ void wait_flag(int* flags, int sp, int lp) {
  if (lp < 0 || lp > 2) return;
  if (sp < lp || sp > lp + T_ - 1) return;
  const int tgt = (lp == 0) ? NB0 : NB12;
  int spin = 0;
  while (__hip_atomic_load(&flags[sp * 3 + lp], __ATOMIC_RELAXED,
                           __HIP_MEMORY_SCOPE_AGENT) < tgt) {
    __builtin_amdgcn_s_sleep(2);
    if (++spin > 2000000) break;
  }
}

// K-loop with DMA-staged A ring. Each wave stages its OWN 32 M-rows (rows
// [m0,m0+32)) into its private slab of each ring slot -> no intra-loop barrier.
template <int NT, int NSTG, int NC, int XKC>
__device__ __forceinline__ void gemm_dma(
    const _Float16* __restrict__ lwW, _Float16* __restrict__ lwA,
    const _Float16* __restrict__ xsrc, int xstrE,
    const _Float16* __restrict__ hown,
    int m0, int lane, floatx4 (&acc)[2][NT]) {
  const int lr = lane & 15, quad = lane >> 4;
  const int rrow = lane >> 2, rq = lane & 3;   // lane -> (row, 16B-quarter) for DMA

  const char* xb = (const char*)xsrc;
  const char* hb = (const char*)hown;
  const size_t xo0 = ((size_t)(m0 + rrow) * xstrE + rq * 8) * 2;
  const size_t xo1 = ((size_t)(m0 + 16 + rrow) * xstrE + rq * 8) * 2;
  const size_t ho0 = ((size_t)(m0 + rrow) * H_ + rq * 8) * 2;
  const size_t ho1 = ((size_t)(m0 + 16 + rrow) * H_ + rq * 8) * 2;

  auto issue = [&](int c) {
    const int slot = c % NSTG;
    char* ld = (char*)lwA + ((size_t)slot * 320 + m0) * 64;   // wave-private slab
    if (c < XKC) {
      const char* g = xb + (size_t)c * 64;
      dma16(g + xo0, ld);
      dma16(g + xo1, ld + 1024);
    } else {
      const char* g = hb + (size_t)(c - XKC) * 64;
      dma16(g + ho0, ld);
      dma16(g + ho1, ld + 1024);
    }
  };

#pragma unroll
  for (int p = 0; p < NSTG; ++p) issue(p);

#pragma unroll
  for (int c = 0; c < NC; ++c) {
    const int slot = c % NSTG;
    waitvm<2 * (NSTG - 1)>();                  // oldest chunk's 2 DMAs landed
    const _Float16* aB = lwA + ((size_t)slot * 320 + m0 + lr) * 32 + quad * 8;
    half8 a0 = *(const half8*)(aB);
    half8 a1 = *(const half8*)(aB + 16 * 32);
    half8 bf[NT];
#pragma unroll
    for (int nt = 0; nt < NT; ++nt)
      bf[nt] = *(const half8*)(lwW + ((size_t)(c * NT * 16 + nt * 16 + lr) * 32 + quad * 8));
#pragma unroll
    for (int nt = 0; nt < NT; ++nt) {
      acc[0][nt] = __builtin_amdgcn_mfma_f32_16x16x32_f16(a0, bf[nt], acc[0][nt], 0, 0, 0);
      acc[1][nt] = __builtin_amdgcn_mfma_f32_16x16x32_f16(a1, bf[nt], acc[1][nt], 0, 0, 0);
    }
    // refill the slot just consumed (reads retired: compiler waits lgkm before MFMA,
    // and the DMA's LDS write lands >= a global-latency after issue)
    if (c + NSTG < NC) issue(c + NSTG);
  }
}

__global__ __launch_bounds__(640)
void lstm_persist(const _Float16* __restrict__ x0,
                  const _Float16* __restrict__ Wc0, const _Float16* __restrict__ Wc1,
                  const _Float16* __restrict__ Wc2,
                  const float* __restrict__ bias, _Float16* __restrict__ hbuf,
                  int* __restrict__ flags) {
  extern __shared__ _Float16 lw[];
  const int bid = blockIdx.x;

  int layer, tile, units, K;
  const _Float16* Wsrc;
  if (bid < NB0)            { layer = 0; tile = bid;              units = 16; K = K0_;  Wsrc = Wc0; }
  else if (bid < NB0+NB12)  { layer = 1; tile = bid - NB0;        units = 8;  K = K12_; Wsrc = Wc1; }
  else                      { layer = 2; tile = bid - NB0 - NB12; units = 8;  K = K12_; Wsrc = Wc2; }
  const int nrows = units * 4;
  const int j0 = tile * units;
  _Float16* lwA = lw + (size_t)(K / 32) * nrows * 32;   // A-ring after weights

  // one-time: stage weight slice into LDS, chunk-major layout
  {
    const int total = (K / 32) * nrows * 4;
    for (int idx = threadIdx.x; idx < total; idx += 640) {
      int c = idx / (nrows * 4);
      int rem = idx % (nrows * 4);
      int r = rem >> 2;
      int q = rem & 3;
      int grow = (r / units) * H_ + j0 + (r % units);
      half8 v = *(const half8*)(Wsrc + (size_t)grow * K + c * 32 + q * 8);
      *(half8*)(lw + ((size_t)(c * nrows + r) * 32 + q * 8)) = v;
    }
  }
  __syncthreads();

  const int lane = threadIdx.x & 63;
  const int wv = threadIdx.x >> 6;      // 10 waves
  const int lr = lane & 15;
  const int quad = lane >> 4;
  const int m0 = wv * 32;
  const int m1 = wv * 32 + 16;
  const int j = j0 + ((units == 16) ? lr : (lr & 7));

  const float bI = bias[layer * G4_ + 0 * H_ + j];
  const float bF = bias[layer * G4_ + 1 * H_ + j];
  const float bG = bias[layer * G4_ + 2 * H_ + j];
  const float bO = bias[layer * G4_ + 3 * H_ + j];

  float cst[2][4] = {{0.f, 0.f, 0.f, 0.f}, {0.f, 0.f, 0.f, 0.f}};

  for (int t = 0; t < T_; ++t) {
    const int s = layer + t;

    // producer waits (true deps)
    if (threadIdx.x == 0) {
      wait_flag(flags, s - 1, layer - 1);
      wait_flag(flags, s - 1, layer);
      __builtin_amdgcn_fence(__ATOMIC_ACQUIRE, "agent");
    }
    __syncthreads();

    const int pprev = (s - 1) & 1;
    const int pcur = s & 1;
    const _Float16* xsrc;
    int xstrE;
    if (layer == 0) { xsrc = x0 + (size_t)t * XP_; xstrE = T_ * XP_; }
    else { xsrc = hbuf + (size_t)((layer - 1) * 2 + pprev) * B_ * H_; xstrE = H_; }
    const _Float16* hown = hbuf + (size_t)(layer * 2 + pprev) * B_ * H_;
    _Float16* hout = hbuf + (size_t)(layer * 2 + pcur) * B_ * H_;

    floatx4 acc0[2][4];
    floatx4 acc2[2][2];
    if (layer == 0) {
#pragma unroll
      for (int a = 0; a < 2; ++a)
#pragma unroll
        for (int b = 0; b < 4; ++b) acc0[a][b] = (floatx4){0.f, 0.f, 0.f, 0.f};
      gemm_dma<4, 2, K0_ / 32, XP_ / 32>(lw, lwA, xsrc, xstrE, hown, m0, lane, acc0);
    } else {
#pragma unroll
      for (int a = 0; a < 2; ++a)
#pragma unroll
        for (int b = 0; b < 2; ++b) acc2[a][b] = (floatx4){0.f, 0.f, 0.f, 0.f};
      gemm_dma<2, 3, K12_ / 32, H_ / 32>(lw, lwA, xsrc, xstrE, hown, m0, lane, acc2);
    }

    // anti-dep wait (cross-layer consumer of buffer (l,pcur)), hidden behind GEMM
    if (threadIdx.x == 0) wait_flag(flags, s - 1, layer + 1);
    __syncthreads();

    if (layer == 0) {
#pragma unroll
      for (int mt = 0; mt < 2; ++mt)
#pragma unroll
        for (int r = 0; r < 4; ++r) {
          float iv = acc0[mt][0][r] + bI;
          float fv = acc0[mt][1][r] + bF;
          float gv = acc0[mt][2][r] + bG;
          float ov = acc0[mt][3][r] + bO;
          float cn = sigm(fv) * cst[mt][r] + sigm(iv) * tanh_f(gv);
          cst[mt][r] = cn;
          int m = (mt ? m1 : m0) + quad * 4 + r;
          hout[(size_t)m * H_ + j] = (_Float16)(sigm(ov) * tanh_f(cn));
        }
    } else {
      // tile0 cols: i,f (units 0..7); tile1: g,o. xor-8 colocates the 4 gates.
#pragma unroll
      for (int mt = 0; mt < 2; ++mt)
#pragma unroll
        for (int r = 0; r < 4; ++r) {
          float t0 = acc2[mt][0][r], t1 = acc2[mt][1][r];
          float p0 = __shfl_xor(t0, 8, 64);
          float p1 = __shfl_xor(t1, 8, 64);
          bool lo = (lr < 8);
          float iv = (lo ? t0 : p0) + bI;
          float fv = (lo ? p0 : t0) + bF;
          float gv = (lo ? t1 : p1) + bG;
          float ov = (lo ? p1 : t1) + bO;
          float cn = sigm(fv) * cst[mt][r] + sigm(iv) * tanh_f(gv);
          cst[mt][r] = cn;
          if (lo) {
            int m = (mt ? m1 : m0) + quad * 4 + r;
            hout[(size_t)m * H_ + j] = (_Float16)(sigm(ov) * tanh_f(cn));
          }
        }
    }

    __syncthreads();   // drains vmcnt (stores + leftover DMAs) before release
    if (threadIdx.x == 0)
      __hip_atomic_fetch_add(&flags[s * 3 + layer], 1, __ATOMIC_RELEASE,
                             __HIP_MEMORY_SCOPE_AGENT);
  }
}

// ---------------- projection + normalize ----------------
__global__ void dvec_kernel(const _Float16* __restrict__ hlast, const float* __restrict__ Wproj,
                            const float* __restrict__ bproj, float* __restrict__ d3) {
  const int m = blockIdx.x;
  const int d = threadIdx.x;
  const _Float16* h = hlast + (size_t)m * H_;
  const float* w = Wproj + (size_t)d * H_;
  float acc = bproj[d];
  for (int k = 0; k < H_; k++) acc += (float)h[k] * w[k];
  __shared__ float red[256];
  red[d] = acc * acc;
  __syncthreads();
  for (int off = 128; off > 0; off >>= 1) {
    if (d < off) red[d] += red[d + off];
    __syncthreads();
  }
  float nrm = sqrtf(red[0]);
  d3[(size_t)m * D_ + d] = acc / nrm;
}

// ---------------- GE2E ----------------
__device__ float block_reduce_sum(float x, float* red) {
  const int d = threadIdx.x;
  red[d] = x;
  __syncthreads();
  for (int off = 128; off > 0; off >>= 1) {
    if (d < off) red[d] += red[d + off];
    __syncthreads();
  }
  float r = red[0];
  __syncthreads();
  return r;
}

__global__ void cent_kernel(const float* __restrict__ d3, float* __restrict__ cent,
                            float* __restrict__ ncent) {
  const int sIdx = blockIdx.x;
  const int d = threadIdx.x;
  float acc = 0.f;
  for (int u = 0; u < U_; u++) acc += d3[((size_t)sIdx * U_ + u) * D_ + d];
  acc *= (1.f / U_);
  cent[sIdx * D_ + d] = acc;
  __shared__ float red[256];
  float n2 = block_reduce_sum(acc * acc, red);
  if (d == 0) ncent[sIdx] = fmaxf(sqrtf(n2), 1e-8f);
}

__global__ void ge2e_kernel(const float* __restrict__ d3, const float* __restrict__ cent,
                            const float* __restrict__ ncent, const float* __restrict__ loss_w,
                            const float* __restrict__ loss_b, float* __restrict__ accums) {
  const int p = blockIdx.x;
  const int sIdx = p / U_;
  const int d = threadIdx.x;
  __shared__ float red[256];
  __shared__ float sims[S_];

  const float v = d3[(size_t)p * D_ + d];
  const float cs = cent[sIdx * D_ + d];
  const float pc = (cs * U_ - v) * (1.f / (U_ - 1));

  float nv2 = block_reduce_sum(v * v, red);
  float npc2 = block_reduce_sum(pc * pc, red);
  float dotp = block_reduce_sum(v * pc, red);

  const float w = loss_w[0], b = loss_b[0];
  const float na = fmaxf(sqrtf(nv2), 1e-6f);
  const float npc = fmaxf(sqrtf(npc2), 1e-6f);
  const float pos_sim = w * (dotp / (na * npc)) + b;
  const float nd = fmaxf(sqrtf(nv2), 1e-8f);

  for (int k = 0; k < S_; k++) {
    float dk = block_reduce_sum(v * cent[k * D_ + d], red);
    if (d == 0) sims[k] = w * (dk / (nd * ncent[k])) + b;
  }
  __syncthreads();
  if (d == 0) {
    float mx = -1e30f;
    for (int k = 0; k < S_; k++)
      if (k != sIdx) mx = fmaxf(mx, sims[k]);
    float se = 0.f, sn = 0.f;
    for (int k = 0; k < S_; k++)
      if (k != sIdx) { se += expf(sims[k] - mx); sn += sims[k]; }
    float lse = mx + logf(se);
    atomicAdd(&accums[0], -pos_sim + lse);
    atomicAdd(&accums[1], pos_sim);
    atomicAdd(&accums[2], sn);
  }
}

__global__ void finalize_kernel(const float* __restrict__ accums, float* __restrict__ out) {
  if (threadIdx.x == 0) {
    out[0] = accums[0] / (float)(S_ * U_);
    out[1] = accums[1] / (float)(S_ * U_);
    out[2] = accums[2] / (float)(S_ * U_ * (S_ - 1));
  }
}

// ---------------- launch ----------------
extern "C" void kernel_launch(void* const* d_in, const int* in_sizes, int n_in,
                              void* d_out, int out_size, void* d_ws, size_t ws_size,
                              hipStream_t stream) {
  const float* mel = (const float*)d_in[0];
  const float* Wih[3] = {(const float*)d_in[1], (const float*)d_in[5], (const float*)d_in[9]};
  const float* Whh[3] = {(const float*)d_in[2], (const float*)d_in[6], (const float*)d_in[10]};
  const float* bih[3] = {(const float*)d_in[3], (const float*)d_in[7], (const float*)d_in[11]};
  const float* bhh[3] = {(const float*)d_in[4], (const float*)d_in[8], (const float*)d_in[12]};
  const float* Wproj = (const float*)d_in[13];
  const float* bproj = (const float*)d_in[14];
  const float* loss_w = (const float*)d_in[15];
  const float* loss_b = (const float*)d_in[16];
  float* out = (float*)d_out;

  char* ws = (char*)d_ws;
  size_t off = 0;
  auto alloc = [&](size_t bytes) -> void* {
    void* p = ws + off;
    off = (off + bytes + 255) & ~(size_t)255;
    return p;
  };
  _Float16* x0   = (_Float16*)alloc((size_t)B_ * T_ * XP_ * 2);
  _Float16* Wc0  = (_Float16*)alloc((size_t)G4_ * K0_ * 2);
  _Float16* Wc1  = (_Float16*)alloc((size_t)G4_ * K12_ * 2);
  _Float16* Wc2  = (_Float16*)alloc((size_t)G4_ * K12_ * 2);
  float*    bias = (float*)alloc((size_t)3 * G4_ * 4);
  _Float16* hbuf = (_Float16*)alloc((size_t)6 * B_ * H_ * 2);
  float*    d3   = (float*)alloc((size_t)B_ * D_ * 4);
  float*    cent = (float*)alloc((size_t)S_ * D_ * 4);
  float*    ncent = (float*)alloc((size_t)S_ * 4);
  float*    accums = (float*)alloc(64);
  int*      flags = (int*)alloc((size_t)(T_ + 3) * 3 * 4);

  hipMemsetAsync(hbuf, 0, (size_t)6 * B_ * H_ * 2, stream);
  hipMemsetAsync(accums, 0, 64, stream);
  hipMemsetAsync(flags, 0, (size_t)(T_ + 3) * 3 * 4, stream);

  prep_x0<<<(B_ * T_ * XP_ + 255) / 256, 256, 0, stream>>>(mel, x0);
  prep_w0<<<(G4_ * K0_ + 255) / 256, 256, 0, stream>>>(Wih[0], Whh[0], Wc0);
  prep_w12<<<(G4_ * K12_ + 255) / 256, 256, 0, stream>>>(Wih[1], Whh[1], Wc1);
  prep_w12<<<(G4_ * K12_ + 255) / 256, 256, 0, stream>>>(Wih[2], Whh[2], Wc2);
  for (int l = 0; l < 3; l++)
    prep_bias<<<(G4_ + 255) / 256, 256, 0, stream>>>(bih[l], bhh[l], bias + l * G4_);

  hipFuncSetAttribute((const void*)lstm_persist,
                      hipFuncAttributeMaxDynamicSharedMemorySize, SMEM_BYTES);
  void* kargs[] = {(void*)&x0, (void*)&Wc0, (void*)&Wc1, (void*)&Wc2,
                   (void*)&bias, (void*)&hbuf, (void*)&flags};
  hipLaunchCooperativeKernel((const void*)lstm_persist, dim3(NBLK), dim3(640),
                             kargs, SMEM_BYTES, stream);

  const _Float16* hlast = hbuf + (size_t)(2 * 2 + 1) * B_ * H_;
  dvec_kernel<<<B_, 256, 0, stream>>>(hlast, Wproj, bproj, d3);
  cent_kernel<<<S_, 256, 0, stream>>>(d3, cent, ncent);
  ge2e_kernel<<<B_, 256, 0, stream>>>(d3, cent, ncent, loss_w, loss_b, accums);
  finalize_kernel<<<1, 64, 0, stream>>>(accums, out);
}

// Round 6
// 4401.051 us; speedup vs baseline: 1.3759x; 1.1663x over previous
//
#include <hip/hip_runtime.h>
#include <math.h>

// Problem constants
#define S_    32
#define U_    10
#define B_    320           // S*U sequences
#define T_    120
#define NMEL_ 40
#define H_    768
#define G4_   3072          // 4*H gates
#define D_    256
#define XP_   64            // mel features zero-padded 40 -> 64
#define K0_   (XP_ + H_)    // 832, layer-0 fused K
#define K12_  (2 * H_)      // 1536, layers 1/2 fused K

#define NB0   48            // layer-0 blocks (16 units each)
#define NB12  96            // layer-1/2 blocks (8 units each)
#define NBLK  (NB0 + 2 * NB12)  // 240 blocks, 1 per CU

// LDS: weights chunk-major, 64 B rows, XOR-swizzled quarters; then A-stage ring.
// layers 1/2: 48*32*64 = 98,304 weights + 3*20,480 ring = 159,744
// layer 0:    26*64*64 = 106,496 weights + 2*20,480 ring = 147,456
#define SMEM_BYTES 159744

typedef _Float16 half8 __attribute__((ext_vector_type(8)));
typedef float floatx4 __attribute__((ext_vector_type(4)));

__device__ __forceinline__ float sigm(float x) {
  return 1.f / (1.f + __expf(-x));
}
__device__ __forceinline__ float tanh_f(float x) {
  x = fminf(15.f, fmaxf(-15.f, x));
  float e = __expf(2.f * x);
  return (e - 1.f) / (e + 1.f);
}

// async global->LDS DMA, 16 B per lane; LDS dest = wave-uniform base + lane*16
__device__ __forceinline__ void dma16(const void* g, void* l) {
  __builtin_amdgcn_global_load_lds(
      (const __attribute__((address_space(1))) unsigned int*)g,
      (__attribute__((address_space(3))) unsigned int*)l, 16, 0, 0);
}

// s_waitcnt vmcnt(N) only (expcnt/lgkmcnt all-ones = no wait)
template <int N>
__device__ __forceinline__ void waitvm() {
  __builtin_amdgcn_s_waitcnt(0x3FF0 | (N & 0xF) | ((N >> 4) << 14));
}

// ---------------- prep kernels ----------------

__global__ void prep_x0(const float* __restrict__ mel, _Float16* __restrict__ x0) {
  int idx = blockIdx.x * 256 + threadIdx.x;
  if (idx >= B_ * T_ * XP_) return;
  int k = idx & (XP_ - 1);
  int t = (idx >> 6) % T_;
  int b = idx / (XP_ * T_);
  float v = (k < NMEL_) ? mel[((size_t)b * NMEL_ + k) * T_ + t] : 0.f;
  x0[idx] = (_Float16)v;
}

__global__ void prep_w0(const float* __restrict__ Wih, const float* __restrict__ Whh,
                        _Float16* __restrict__ Wc) {
  int idx = blockIdx.x * 256 + threadIdx.x;
  if (idx >= G4_ * K0_) return;
  int k = idx % K0_;
  int n = idx / K0_;
  float v = 0.f;
  if (k < NMEL_)      v = Wih[(size_t)n * NMEL_ + k];
  else if (k >= XP_)  v = Whh[(size_t)n * H_ + (k - XP_)];
  Wc[idx] = (_Float16)v;
}

__global__ void prep_w12(const float* __restrict__ Wih, const float* __restrict__ Whh,
                         _Float16* __restrict__ Wc) {
  int idx = blockIdx.x * 256 + threadIdx.x;
  if (idx >= G4_ * K12_) return;
  int k = idx % K12_;
  int n = idx / K12_;
  float v = (k < H_) ? Wih[(size_t)n * H_ + k] : Whh[(size_t)n * H_ + (k - H_)];
  Wc[idx] = (_Float16)v;
}

__global__ void prep_bias(const float* __restrict__ bih, const float* __restrict__ bhh,
                          float* __restrict__ bias) {
  int idx = blockIdx.x * 256 + threadIdx.x;
  if (idx < G4_) bias[idx] = bih[idx] + bhh[idx];
}

// ---------------- persistent LSTM ----------------

// Per-block completion slots: fl[((s*3)+lp)*96 + blk], release-stored 1 when
// block blk of layer lp finished grid-step s. Wave-parallel polling.
__device__ __forceinline__ void wait_group(int* fl, int sp, int lp, int lane) {
  if (lp < 0 || lp > 2) return;
  if (sp < lp || sp > lp + T_ - 1) return;
  const int tgt = (lp == 0) ? NB0 : NB12;
  const int base = (sp * 3 + lp) * 96;
  int spin = 0;
  for (;;) {
    int v0 = (lane < tgt)
                 ? __hip_atomic_load(&fl[base + lane], __ATOMIC_RELAXED,
                                     __HIP_MEMORY_SCOPE_AGENT) : 1;
    int v1 = (lane + 64 < tgt)
                 ? __hip_atomic_load(&fl[base + 64 + lane], __ATOMIC_RELAXED,
                                     __HIP_MEMORY_SCOPE_AGENT) : 1;
    if (__all(v0 != 0 && v1 != 0)) break;
    __builtin_amdgcn_s_sleep(1);
    if (++spin > 2000000) break;     // bounded: fail as absmax, not hang
  }
}

// K-loop with DMA-staged A ring, XOR-swizzled quarters. Each wave stages its
// OWN 32 M-rows into its private slab of each ring slot -> no intra-loop barrier.
template <int NT, int NSTG, int NC, int XKC>
__device__ __forceinline__ void gemm_dma(
    const _Float16* __restrict__ lwW, _Float16* __restrict__ lwA,
    const _Float16* __restrict__ xsrc, int xstrE,
    const _Float16* __restrict__ hown,
    int m0, int lane, floatx4 (&acc)[2][NT]) {
  const int lr = lane & 15, quad = lane >> 4;
  const int rrow = lane >> 2, rq = lane & 3;       // lane -> (row, 16B-quarter)
  const int rqs = rq ^ ((rrow >> 1) & 3);          // swizzled global quarter

  const char* xb = (const char*)xsrc;
  const char* hb = (const char*)hown;
  const size_t xo0 = ((size_t)(m0 + rrow) * xstrE + rqs * 8) * 2;
  const size_t xo1 = ((size_t)(m0 + 16 + rrow) * xstrE + rqs * 8) * 2;
  const size_t ho0 = ((size_t)(m0 + rrow) * H_ + rqs * 8) * 2;
  const size_t ho1 = ((size_t)(m0 + 16 + rrow) * H_ + rqs * 8) * 2;

  auto issue = [&](int c) {
    const int slot = c % NSTG;
    char* ld = (char*)lwA + ((size_t)slot * 320 + m0) * 64;   // wave-private slab
    if (c < XKC) {
      const char* g = xb + (size_t)c * 64;
      dma16(g + xo0, ld);
      dma16(g + xo1, ld + 1024);
    } else {
      const char* g = hb + (size_t)(c - XKC) * 64;
      dma16(g + ho0, ld);
      dma16(g + ho1, ld + 1024);
    }
  };

#pragma unroll
  for (int p = 0; p < NSTG; ++p) issue(p);

  const int asw = (quad ^ ((lr >> 1) & 3)) * 8;    // A-read swizzled quarter (halves)

#pragma unroll
  for (int c = 0; c < NC; ++c) {
    const int slot = c % NSTG;
    waitvm<2 * (NSTG - 1)>();                      // oldest chunk's 2 DMAs landed
    const _Float16* aB = lwA + ((size_t)slot * 320 + m0 + lr) * 32 + asw;
    half8 a0 = *(const half8*)(aB);
    half8 a1 = *(const half8*)(aB + 16 * 32);
    half8 bf[NT];
#pragma unroll
    for (int nt = 0; nt < NT; ++nt)
      bf[nt] = *(const half8*)(lwW + ((size_t)(c * NT * 16 + nt * 16 + lr) * 32 + asw));
#pragma unroll
    for (int nt = 0; nt < NT; ++nt) {
      acc[0][nt] = __builtin_amdgcn_mfma_f32_16x16x32_f16(a0, bf[nt], acc[0][nt], 0, 0, 0);
      acc[1][nt] = __builtin_amdgcn_mfma_f32_16x16x32_f16(a1, bf[nt], acc[1][nt], 0, 0, 0);
    }
    if (c + NSTG < NC) issue(c + NSTG);            // refill the slot just consumed
  }
}

__global__ __launch_bounds__(640)
void lstm_persist(const _Float16* __restrict__ x0,
                  const _Float16* __restrict__ Wc0, const _Float16* __restrict__ Wc1,
                  const _Float16* __restrict__ Wc2,
                  const float* __restrict__ bias, _Float16* __restrict__ hbuf,
                  int* __restrict__ flags) {
  extern __shared__ _Float16 lw[];
  const int bid = blockIdx.x;

  int layer, tile, units, K;
  const _Float16* Wsrc;
  if (bid < NB0)            { layer = 0; tile = bid;              units = 16; K = K0_;  Wsrc = Wc0; }
  else if (bid < NB0+NB12)  { layer = 1; tile = bid - NB0;        units = 8;  K = K12_; Wsrc = Wc1; }
  else                      { layer = 2; tile = bid - NB0 - NB12; units = 8;  K = K12_; Wsrc = Wc2; }
  const int nrows = units * 4;
  const int j0 = tile * units;
  _Float16* lwA = lw + (size_t)(K / 32) * nrows * 32;   // A-ring after weights

  // one-time: stage weight slice into LDS, chunk-major + XOR-swizzled quarters
  {
    const int total = (K / 32) * nrows * 4;
    for (int idx = threadIdx.x; idx < total; idx += 640) {
      int c = idx / (nrows * 4);
      int rem = idx % (nrows * 4);
      int r = rem >> 2;
      int q = rem & 3;
      int grow = (r / units) * H_ + j0 + (r % units);
      half8 v = *(const half8*)(Wsrc + (size_t)grow * K + c * 32 + q * 8);
      int qs = q ^ ((r >> 1) & 3);
      *(half8*)(lw + ((size_t)(c * nrows + r) * 32 + qs * 8)) = v;
    }
  }
  __syncthreads();

  const int lane = threadIdx.x & 63;
  const int wv = threadIdx.x >> 6;      // 10 waves
  const int lr = lane & 15;
  const int quad = lane >> 4;
  const int m0 = wv * 32;
  const int m1 = wv * 32 + 16;
  const int j = j0 + ((units == 16) ? lr : (lr & 7));

  const float bI = bias[layer * G4_ + 0 * H_ + j];
  const float bF = bias[layer * G4_ + 1 * H_ + j];
  const float bG = bias[layer * G4_ + 2 * H_ + j];
  const float bO = bias[layer * G4_ + 3 * H_ + j];

  float cst[2][4] = {{0.f, 0.f, 0.f, 0.f}, {0.f, 0.f, 0.f, 0.f}};

  for (int t = 0; t < T_; ++t) {
    const int s = layer + t;

    // producer waits (true deps) — wave 0 polls per-block slots in parallel
    if (wv == 0) {
      wait_group(flags, s - 1, layer - 1, lane);
      wait_group(flags, s - 1, layer, lane);
      __builtin_amdgcn_fence(__ATOMIC_ACQUIRE, "agent");   // one cache-inv per step
    }
    __syncthreads();

    const int pprev = (s - 1) & 1;
    const int pcur = s & 1;
    const _Float16* xsrc;
    int xstrE;
    if (layer == 0) { xsrc = x0 + (size_t)t * XP_; xstrE = T_ * XP_; }
    else { xsrc = hbuf + (size_t)((layer - 1) * 2 + pprev) * B_ * H_; xstrE = H_; }
    const _Float16* hown = hbuf + (size_t)(layer * 2 + pprev) * B_ * H_;
    _Float16* hout = hbuf + (size_t)(layer * 2 + pcur) * B_ * H_;

    floatx4 acc0[2][4];
    floatx4 acc2[2][2];
    if (layer == 0) {
#pragma unroll
      for (int a = 0; a < 2; ++a)
#pragma unroll
        for (int b = 0; b < 4; ++b) acc0[a][b] = (floatx4){0.f, 0.f, 0.f, 0.f};
      gemm_dma<4, 2, K0_ / 32, XP_ / 32>(lw, lwA, xsrc, xstrE, hown, m0, lane, acc0);
    } else {
#pragma unroll
      for (int a = 0; a < 2; ++a)
#pragma unroll
        for (int b = 0; b < 2; ++b) acc2[a][b] = (floatx4){0.f, 0.f, 0.f, 0.f};
      gemm_dma<2, 3, K12_ / 32, H_ / 32>(lw, lwA, xsrc, xstrE, hown, m0, lane, acc2);
    }

    // anti-dep wait (cross-layer consumer of buffer (l,pcur)), hidden behind GEMM
    if (wv == 0) wait_group(flags, s - 1, layer + 1, lane);
    __syncthreads();

    if (layer == 0) {
#pragma unroll
      for (int mt = 0; mt < 2; ++mt)
#pragma unroll
        for (int r = 0; r < 4; ++r) {
          float iv = acc0[mt][0][r] + bI;
          float fv = acc0[mt][1][r] + bF;
          float gv = acc0[mt][2][r] + bG;
          float ov = acc0[mt][3][r] + bO;
          float cn = sigm(fv) * cst[mt][r] + sigm(iv) * tanh_f(gv);
          cst[mt][r] = cn;
          int m = (mt ? m1 : m0) + quad * 4 + r;
          hout[(size_t)m * H_ + j] = (_Float16)(sigm(ov) * tanh_f(cn));
        }
    } else {
      // tile0 cols: i,f (units 0..7); tile1: g,o. xor-8 colocates the 4 gates.
#pragma unroll
      for (int mt = 0; mt < 2; ++mt)
#pragma unroll
        for (int r = 0; r < 4; ++r) {
          float t0 = acc2[mt][0][r], t1 = acc2[mt][1][r];
          float p0 = __shfl_xor(t0, 8, 64);
          float p1 = __shfl_xor(t1, 8, 64);
          bool lo = (lr < 8);
          float iv = (lo ? t0 : p0) + bI;
          float fv = (lo ? p0 : t0) + bF;
          float gv = (lo ? t1 : p1) + bG;
          float ov = (lo ? p1 : t1) + bO;
          float cn = sigm(fv) * cst[mt][r] + sigm(iv) * tanh_f(gv);
          cst[mt][r] = cn;
          if (lo) {
            int m = (mt ? m1 : m0) + quad * 4 + r;
            hout[(size_t)m * H_ + j] = (_Float16)(sigm(ov) * tanh_f(cn));
          }
        }
    }

    __syncthreads();   // drains vmcnt (stores + leftover DMAs) before release
    if (threadIdx.x == 0)
      __hip_atomic_store(&flags[(s * 3 + layer) * 96 + tile], 1, __ATOMIC_RELEASE,
                         __HIP_MEMORY_SCOPE_AGENT);
  }
}

// ---------------- projection + normalize ----------------
__global__ void dvec_kernel(const _Float16* __restrict__ hlast, const float* __restrict__ Wproj,
                            const float* __restrict__ bproj, float* __restrict__ d3) {
  const int m = blockIdx.x;
  const int d = threadIdx.x;
  const _Float16* h = hlast + (size_t)m * H_;
  const float* w = Wproj + (size_t)d * H_;
  float acc = bproj[d];
  for (int k = 0; k < H_; k++) acc += (float)h[k] * w[k];
  __shared__ float red[256];
  red[d] = acc * acc;
  __syncthreads();
  for (int off = 128; off > 0; off >>= 1) {
    if (d < off) red[d] += red[d + off];
    __syncthreads();
  }
  float nrm = sqrtf(red[0]);
  d3[(size_t)m * D_ + d] = acc / nrm;
}

// ---------------- GE2E ----------------
__device__ float block_reduce_sum(float x, float* red) {
  const int d = threadIdx.x;
  red[d] = x;
  __syncthreads();
  for (int off = 128; off > 0; off >>= 1) {
    if (d < off) red[d] += red[d + off];
    __syncthreads();
  }
  float r = red[0];
  __syncthreads();
  return r;
}

__global__ void cent_kernel(const float* __restrict__ d3, float* __restrict__ cent,
                            float* __restrict__ ncent) {
  const int sIdx = blockIdx.x;
  const int d = threadIdx.x;
  float acc = 0.f;
  for (int u = 0; u < U_; u++) acc += d3[((size_t)sIdx * U_ + u) * D_ + d];
  acc *= (1.f / U_);
  cent[sIdx * D_ + d] = acc;
  __shared__ float red[256];
  float n2 = block_reduce_sum(acc * acc, red);
  if (d == 0) ncent[sIdx] = fmaxf(sqrtf(n2), 1e-8f);
}

__global__ void ge2e_kernel(const float* __restrict__ d3, const float* __restrict__ cent,
                            const float* __restrict__ ncent, const float* __restrict__ loss_w,
                            const float* __restrict__ loss_b, float* __restrict__ accums) {
  const int p = blockIdx.x;
  const int sIdx = p / U_;
  const int d = threadIdx.x;
  __shared__ float red[256];
  __shared__ float sims[S_];

  const float v = d3[(size_t)p * D_ + d];
  const float cs = cent[sIdx * D_ + d];
  const float pc = (cs * U_ - v) * (1.f / (U_ - 1));

  float nv2 = block_reduce_sum(v * v, red);
  float npc2 = block_reduce_sum(pc * pc, red);
  float dotp = block_reduce_sum(v * pc, red);

  const float w = loss_w[0], b = loss_b[0];
  const float na = fmaxf(sqrtf(nv2), 1e-6f);
  const float npc = fmaxf(sqrtf(npc2), 1e-6f);
  const float pos_sim = w * (dotp / (na * npc)) + b;
  const float nd = fmaxf(sqrtf(nv2), 1e-8f);

  for (int k = 0; k < S_; k++) {
    float dk = block_reduce_sum(v * cent[k * D_ + d], red);
    if (d == 0) sims[k] = w * (dk / (nd * ncent[k])) + b;
  }
  __syncthreads();
  if (d == 0) {
    float mx = -1e30f;
    for (int k = 0; k < S_; k++)
      if (k != sIdx) mx = fmaxf(mx, sims[k]);
    float se = 0.f, sn = 0.f;
    for (int k = 0; k < S_; k++)
      if (k != sIdx) { se += expf(sims[k] - mx); sn += sims[k]; }
    float lse = mx + logf(se);
    atomicAdd(&accums[0], -pos_sim + lse);
    atomicAdd(&accums[1], pos_sim);
    atomicAdd(&accums[2], sn);
  }
}

__global__ void finalize_kernel(const float* __restrict__ accums, float* __restrict__ out) {
  if (threadIdx.x == 0) {
    out[0] = accums[0] / (float)(S_ * U_);
    out[1] = accums[1] / (float)(S_ * U_);
    out[2] = accums[2] / (float)(S_ * U_ * (S_ - 1));
  }
}

// ---------------- launch ----------------
extern "C" void kernel_launch(void* const* d_in, const int* in_sizes, int n_in,
                              void* d_out, int out_size, void* d_ws, size_t ws_size,
                              hipStream_t stream) {
  const float* mel = (const float*)d_in[0];
  const float* Wih[3] = {(const float*)d_in[1], (const float*)d_in[5], (const float*)d_in[9]};
  const float* Whh[3] = {(const float*)d_in[2], (const float*)d_in[6], (const float*)d_in[10]};
  const float* bih[3] = {(const float*)d_in[3], (const float*)d_in[7], (const float*)d_in[11]};
  const float* bhh[3] = {(const float*)d_in[4], (const float*)d_in[8], (const float*)d_in[12]};
  const float* Wproj = (const float*)d_in[13];
  const float* bproj = (const float*)d_in[14];
  const float* loss_w = (const float*)d_in[15];
  const float* loss_b = (const float*)d_in[16];
  float* out = (float*)d_out;

  char* ws = (char*)d_ws;
  size_t off = 0;
  auto alloc = [&](size_t bytes) -> void* {
    void* p = ws + off;
    off = (off + bytes + 255) & ~(size_t)255;
    return p;
  };
  _Float16* x0   = (_Float16*)alloc((size_t)B_ * T_ * XP_ * 2);
  _Float16* Wc0  = (_Float16*)alloc((size_t)G4_ * K0_ * 2);
  _Float16* Wc1  = (_Float16*)alloc((size_t)G4_ * K12_ * 2);
  _Float16* Wc2  = (_Float16*)alloc((size_t)G4_ * K12_ * 2);
  float*    bias = (float*)alloc((size_t)3 * G4_ * 4);
  _Float16* hbuf = (_Float16*)alloc((size_t)6 * B_ * H_ * 2);
  float*    d3   = (float*)alloc((size_t)B_ * D_ * 4);
  float*    cent = (float*)alloc((size_t)S_ * D_ * 4);
  float*    ncent = (float*)alloc((size_t)S_ * 4);
  float*    accums = (float*)alloc(64);
  int*      flags = (int*)alloc((size_t)(T_ + 3) * 3 * 96 * 4);

  hipMemsetAsync(hbuf, 0, (size_t)6 * B_ * H_ * 2, stream);
  hipMemsetAsync(accums, 0, 64, stream);
  hipMemsetAsync(flags, 0, (size_t)(T_ + 3) * 3 * 96 * 4, stream);

  prep_x0<<<(B_ * T_ * XP_ + 255) / 256, 256, 0, stream>>>(mel, x0);
  prep_w0<<<(G4_ * K0_ + 255) / 256, 256, 0, stream>>>(Wih[0], Whh[0], Wc0);
  prep_w12<<<(G4_ * K12_ + 255) / 256, 256, 0, stream>>>(Wih[1], Whh[1], Wc1);
  prep_w12<<<(G4_ * K12_ + 255) / 256, 256, 0, stream>>>(Wih[2], Whh[2], Wc2);
  for (int l = 0; l < 3; l++)
    prep_bias<<<(G4_ + 255) / 256, 256, 0, stream>>>(bih[l], bhh[l], bias + l * G4_);

  hipFuncSetAttribute((const void*)lstm_persist,
                      hipFuncAttributeMaxDynamicSharedMemorySize, SMEM_BYTES);
  void* kargs[] = {(void*)&x0, (void*)&Wc0, (void*)&Wc1, (void*)&Wc2,
                   (void*)&bias, (void*)&hbuf, (void*)&flags};
  hipLaunchCooperativeKernel((const void*)lstm_persist, dim3(NBLK), dim3(640),
                             kargs, SMEM_BYTES, stream);

  const _Float16* hlast = hbuf + (size_t)(2 * 2 + 1) * B_ * H_;
  dvec_kernel<<<B_, 256, 0, stream>>>(hlast, Wproj, bproj, d3);
  cent_kernel<<<S_, 256, 0, stream>>>(d3, cent, ncent);
  ge2e_kernel<<<B_, 256, 0, stream>>>(d3, cent, ncent, loss_w, loss_b, accums);
  finalize_kernel<<<1, 64, 0, stream>>>(accums, out);
}

// Round 7
// 3268.503 us; speedup vs baseline: 1.8526x; 1.3465x over previous
//
#include <hip/hip_runtime.h>
#include <math.h>

// Problem constants
#define S_    32
#define U_    10
#define B_    320           // S*U sequences
#define T_    120
#define NMEL_ 40
#define H_    768
#define G4_   3072          // 4*H gates
#define D_    256
#define XP_   64            // mel features zero-padded 40 -> 64
#define K0_   (XP_ + H_)    // 832, layer-0 fused K
#define K12_  (2 * H_)      // 1536, layers 1/2 fused K

#define NB0   48            // layer-0 blocks (16 units each)
#define NB12  96            // layer-1/2 blocks (8 units each)
#define NBLK  (NB0 + 2 * NB12)  // 240 blocks, 1 per CU

// LDS: weights chunk-major, 64 B rows, XOR-swizzled quarters; then A-stage ring.
// layers 1/2: 48*32*64 = 98,304 weights + 3*20,480 ring = 159,744
// layer 0:    26*64*64 = 106,496 weights + 2*20,480 ring = 147,456
#define SMEM_BYTES 159744

typedef _Float16 half8 __attribute__((ext_vector_type(8)));
typedef float floatx4 __attribute__((ext_vector_type(4)));

__device__ __forceinline__ float sigm(float x) {
  return 1.f / (1.f + __expf(-x));
}
__device__ __forceinline__ float tanh_f(float x) {
  x = fminf(15.f, fmaxf(-15.f, x));
  float e = __expf(2.f * x);
  return (e - 1.f) / (e + 1.f);
}

// async global->LDS DMA, 16 B per lane; LDS dest = wave-uniform base + lane*16
__device__ __forceinline__ void dma16(const void* g, void* l) {
  __builtin_amdgcn_global_load_lds(
      (const __attribute__((address_space(1))) unsigned int*)g,
      (__attribute__((address_space(3))) unsigned int*)l, 16, 0, 0);
}

// s_waitcnt vmcnt(N) only (expcnt/lgkmcnt all-ones = no wait)
template <int N>
__device__ __forceinline__ void waitvm() {
  __builtin_amdgcn_s_waitcnt(0x3FF0 | (N & 0xF) | ((N >> 4) << 14));
}

// ---------------- prep kernels ----------------

__global__ void prep_x0(const float* __restrict__ mel, _Float16* __restrict__ x0) {
  int idx = blockIdx.x * 256 + threadIdx.x;
  if (idx >= B_ * T_ * XP_) return;
  int k = idx & (XP_ - 1);
  int t = (idx >> 6) % T_;
  int b = idx / (XP_ * T_);
  float v = (k < NMEL_) ? mel[((size_t)b * NMEL_ + k) * T_ + t] : 0.f;
  x0[idx] = (_Float16)v;
}

__global__ void prep_w0(const float* __restrict__ Wih, const float* __restrict__ Whh,
                        _Float16* __restrict__ Wc) {
  int idx = blockIdx.x * 256 + threadIdx.x;
  if (idx >= G4_ * K0_) return;
  int k = idx % K0_;
  int n = idx / K0_;
  float v = 0.f;
  if (k < NMEL_)      v = Wih[(size_t)n * NMEL_ + k];
  else if (k >= XP_)  v = Whh[(size_t)n * H_ + (k - XP_)];
  Wc[idx] = (_Float16)v;
}

__global__ void prep_w12(const float* __restrict__ Wih, const float* __restrict__ Whh,
                         _Float16* __restrict__ Wc) {
  int idx = blockIdx.x * 256 + threadIdx.x;
  if (idx >= G4_ * K12_) return;
  int k = idx % K12_;
  int n = idx / K12_;
  float v = (k < H_) ? Wih[(size_t)n * H_ + k] : Whh[(size_t)n * H_ + (k - H_)];
  Wc[idx] = (_Float16)v;
}

__global__ void prep_bias(const float* __restrict__ bih, const float* __restrict__ bhh,
                          float* __restrict__ bias) {
  int idx = blockIdx.x * 256 + threadIdx.x;
  if (idx < G4_) bias[idx] = bih[idx] + bhh[idx];
}

// ---------------- persistent LSTM ----------------

// Per-block completion slots: fl[((s*3)+lp)*96 + blk]; release-stored 1 when
// block blk of layer lp finished grid-step s. Wave-parallel polling (any wave).
__device__ __forceinline__ void wait_group(int* fl, int sp, int lp, int lane) {
  if (lp < 0 || lp > 2) return;
  if (sp < lp || sp > lp + T_ - 1) return;
  const int tgt = (lp == 0) ? NB0 : NB12;
  const int base = (sp * 3 + lp) * 96;
  int spin = 0;
  for (;;) {
    int v0 = (lane < tgt)
                 ? __hip_atomic_load(&fl[base + lane], __ATOMIC_RELAXED,
                                     __HIP_MEMORY_SCOPE_AGENT) : 1;
    int v1 = (lane + 64 < tgt)
                 ? __hip_atomic_load(&fl[base + 64 + lane], __ATOMIC_RELAXED,
                                     __HIP_MEMORY_SCOPE_AGENT) : 1;
    if (__all(v0 != 0 && v1 != 0)) break;
    __builtin_amdgcn_s_sleep(1);
    if (++spin > 2000000) break;     // bounded: fail as absmax, not hang
  }
}

// One K-phase with DMA-staged A ring (uniform source base), XOR-swizzled
// quarters. Each wave stages its OWN 32 M-rows -> no intra-loop barrier.
// W chunk indices are wchunk0 + c.
template <int NT, int NSTG, int NC>
__device__ __forceinline__ void gemm_phase(
    const _Float16* __restrict__ lwW, int wchunk0, _Float16* __restrict__ lwA,
    const char* __restrict__ src, int strideE,
    int m0, int lane, floatx4 (&acc)[2][NT]) {
  const int lr = lane & 15, quad = lane >> 4;
  const int rrow = lane >> 2, rq = lane & 3;       // lane -> (row, 16B-quarter)
  const int rqs = rq ^ ((rrow >> 1) & 3);          // swizzled global quarter
  const size_t o0 = ((size_t)(m0 + rrow) * strideE + rqs * 8) * 2;
  const size_t o1 = ((size_t)(m0 + 16 + rrow) * strideE + rqs * 8) * 2;

  auto issue = [&](int c) {
    const int slot = c % NSTG;
    char* ld = (char*)lwA + ((size_t)slot * 320 + m0) * 64;   // wave-private slab
    const char* g = src + (size_t)c * 64;
    dma16(g + o0, ld);
    dma16(g + o1, ld + 1024);
  };

#pragma unroll
  for (int p = 0; p < (NSTG < NC ? NSTG : NC); ++p) issue(p);

  const int asw = (quad ^ ((lr >> 1) & 3)) * 8;    // A-read swizzled quarter

#pragma unroll
  for (int c = 0; c < NC; ++c) {
    waitvm<2 * (NSTG - 1)>();                      // chunk c's DMAs landed
    const int slot = c % NSTG;
    const _Float16* aB = lwA + ((size_t)slot * 320 + m0 + lr) * 32 + asw;
    half8 a0 = *(const half8*)(aB);
    half8 a1 = *(const half8*)(aB + 16 * 32);
    half8 bf[NT];
#pragma unroll
    for (int nt = 0; nt < NT; ++nt)
      bf[nt] = *(const half8*)(lwW +
               ((size_t)((wchunk0 + c) * NT * 16 + nt * 16 + lr) * 32 + asw));
#pragma unroll
    for (int nt = 0; nt < NT; ++nt) {
      acc[0][nt] = __builtin_amdgcn_mfma_f32_16x16x32_f16(a0, bf[nt], acc[0][nt], 0, 0, 0);
      acc[1][nt] = __builtin_amdgcn_mfma_f32_16x16x32_f16(a1, bf[nt], acc[1][nt], 0, 0, 0);
    }
    if (c + NSTG < NC) issue(c + NSTG);            // refill the slot just consumed
  }
}

__global__ __launch_bounds__(640)
void lstm_persist(const _Float16* __restrict__ x0,
                  const _Float16* __restrict__ Wc0, const _Float16* __restrict__ Wc1,
                  const _Float16* __restrict__ Wc2,
                  const float* __restrict__ bias, _Float16* __restrict__ hbuf,
                  int* __restrict__ flags) {
  extern __shared__ _Float16 lw[];
  const int bid = blockIdx.x;

  int layer, tile, units, K;
  const _Float16* Wsrc;
  if (bid < NB0)            { layer = 0; tile = bid;              units = 16; K = K0_;  Wsrc = Wc0; }
  else if (bid < NB0+NB12)  { layer = 1; tile = bid - NB0;        units = 8;  K = K12_; Wsrc = Wc1; }
  else                      { layer = 2; tile = bid - NB0 - NB12; units = 8;  K = K12_; Wsrc = Wc2; }
  const int nrows = units * 4;
  const int j0 = tile * units;
  _Float16* lwA = lw + (size_t)(K / 32) * nrows * 32;   // A-ring after weights

  // one-time: stage weight slice into LDS, chunk-major + XOR-swizzled quarters
  {
    const int total = (K / 32) * nrows * 4;
    for (int idx = threadIdx.x; idx < total; idx += 640) {
      int c = idx / (nrows * 4);
      int rem = idx % (nrows * 4);
      int r = rem >> 2;
      int q = rem & 3;
      int grow = (r / units) * H_ + j0 + (r % units);
      half8 v = *(const half8*)(Wsrc + (size_t)grow * K + c * 32 + q * 8);
      int qs = q ^ ((r >> 1) & 3);
      *(half8*)(lw + ((size_t)(c * nrows + r) * 32 + qs * 8)) = v;
    }
  }
  __syncthreads();

  const int lane = threadIdx.x & 63;
  const int wv = threadIdx.x >> 6;      // 10 waves
  const int lr = lane & 15;
  const int quad = lane >> 4;
  const int m0 = wv * 32;
  const int m1 = wv * 32 + 16;
  const int j = j0 + ((units == 16) ? lr : (lr & 7));

  const float bI = bias[layer * G4_ + 0 * H_ + j];
  const float bF = bias[layer * G4_ + 1 * H_ + j];
  const float bG = bias[layer * G4_ + 2 * H_ + j];
  const float bO = bias[layer * G4_ + 3 * H_ + j];

  float cst[2][4] = {{0.f, 0.f, 0.f, 0.f}, {0.f, 0.f, 0.f, 0.f}};

  for (int t = 0; t < T_; ++t) {
    const int s = layer + t;
    const int pprev = (s - 1) & 1;
    const int pcur = s & 1;
    const _Float16* hown = hbuf + (size_t)(layer * 2 + pprev) * B_ * H_;
    _Float16* hout = hbuf + (size_t)(layer * 2 + pcur) * B_ * H_;

    floatx4 acc0[2][4];
    floatx4 acc2[2][2];

    if (layer == 0) {
      // x-phase: x0 is constant -> no wait, no fence
#pragma unroll
      for (int a = 0; a < 2; ++a)
#pragma unroll
        for (int b = 0; b < 4; ++b) acc0[a][b] = (floatx4){0.f, 0.f, 0.f, 0.f};
      const char* xsrc = (const char*)(x0 + (size_t)t * XP_);
      gemm_phase<4, 2, 2>(lw, 0, lwA, xsrc, T_ * XP_, m0, lane, acc0);
      // own-h phase: needs (0, s-1) + one fence (L2 inv) for cross-XCD h
      if (wv == 0) {
        wait_group(flags, s - 1, 0, lane);
        __builtin_amdgcn_fence(__ATOMIC_ACQUIRE, "agent");
      }
      __syncthreads();
      gemm_phase<4, 2, 24>(lw, 2, lwA, (const char*)hown, H_, m0, lane, acc0);
    } else {
      // x-phase: producer (l-1, s-1); single fence per step
      if (wv == 0) {
        wait_group(flags, s - 1, layer - 1, lane);
        __builtin_amdgcn_fence(__ATOMIC_ACQUIRE, "agent");
      }
      __syncthreads();
#pragma unroll
      for (int a = 0; a < 2; ++a)
#pragma unroll
        for (int b = 0; b < 2; ++b) acc2[a][b] = (floatx4){0.f, 0.f, 0.f, 0.f};
      const char* xsrc = (const char*)(hbuf + (size_t)((layer - 1) * 2 + pprev) * B_ * H_);
      gemm_phase<2, 3, 24>(lw, 0, lwA, xsrc, H_, m0, lane, acc2);
      // own-h phase: per-wave wait, NO fence (post-inv L2 fills are fresh),
      // no barrier — hidden behind the x-phase GEMM
      wait_group(flags, s - 1, layer, lane);
      gemm_phase<2, 3, 24>(lw, 24, lwA, (const char*)hown, H_, m0, lane, acc2);
    }

    // anti-dep: (l+1) must be done reading buffer (l, pcur). Per-wave, no fence
    // (no data read), no barrier — each wave then writes its own disjoint rows.
    wait_group(flags, s - 1, layer + 1, lane);

    if (layer == 0) {
#pragma unroll
      for (int mt = 0; mt < 2; ++mt)
#pragma unroll
        for (int r = 0; r < 4; ++r) {
          float iv = acc0[mt][0][r] + bI;
          float fv = acc0[mt][1][r] + bF;
          float gv = acc0[mt][2][r] + bG;
          float ov = acc0[mt][3][r] + bO;
          float cn = sigm(fv) * cst[mt][r] + sigm(iv) * tanh_f(gv);
          cst[mt][r] = cn;
          int m = (mt ? m1 : m0) + quad * 4 + r;
          hout[(size_t)m * H_ + j] = (_Float16)(sigm(ov) * tanh_f(cn));
        }
    } else {
      // tile0 cols: i,f (units 0..7); tile1: g,o. xor-8 colocates the 4 gates.
#pragma unroll
      for (int mt = 0; mt < 2; ++mt)
#pragma unroll
        for (int r = 0; r < 4; ++r) {
          float t0 = acc2[mt][0][r], t1 = acc2[mt][1][r];
          float p0 = __shfl_xor(t0, 8, 64);
          float p1 = __shfl_xor(t1, 8, 64);
          bool lo = (lr < 8);
          float iv = (lo ? t0 : p0) + bI;
          float fv = (lo ? p0 : t0) + bF;
          float gv = (lo ? t1 : p1) + bG;
          float ov = (lo ? p1 : t1) + bO;
          float cn = sigm(fv) * cst[mt][r] + sigm(iv) * tanh_f(gv);
          cst[mt][r] = cn;
          if (lo) {
            int m = (mt ? m1 : m0) + quad * 4 + r;
            hout[(size_t)m * H_ + j] = (_Float16)(sigm(ov) * tanh_f(cn));
          }
        }
    }

    __syncthreads();   // drains vmcnt (all waves' stores) before release
    if (threadIdx.x == 0)
      __hip_atomic_store(&flags[(s * 3 + layer) * 96 + tile], 1, __ATOMIC_RELEASE,
                         __HIP_MEMORY_SCOPE_AGENT);
  }
}

// ---------------- projection + normalize ----------------
__global__ void dvec_kernel(const _Float16* __restrict__ hlast, const float* __restrict__ Wproj,
                            const float* __restrict__ bproj, float* __restrict__ d3) {
  const int m = blockIdx.x;
  const int d = threadIdx.x;
  const _Float16* h = hlast + (size_t)m * H_;
  const float* w = Wproj + (size_t)d * H_;
  float acc = bproj[d];
  for (int k = 0; k < H_; k++) acc += (float)h[k] * w[k];
  __shared__ float red[256];
  red[d] = acc * acc;
  __syncthreads();
  for (int off = 128; off > 0; off >>= 1) {
    if (d < off) red[d] += red[d + off];
    __syncthreads();
  }
  float nrm = sqrtf(red[0]);
  d3[(size_t)m * D_ + d] = acc / nrm;
}

// ---------------- GE2E ----------------
__device__ float block_reduce_sum(float x, float* red) {
  const int d = threadIdx.x;
  red[d] = x;
  __syncthreads();
  for (int off = 128; off > 0; off >>= 1) {
    if (d < off) red[d] += red[d + off];
    __syncthreads();
  }
  float r = red[0];
  __syncthreads();
  return r;
}

__global__ void cent_kernel(const float* __restrict__ d3, float* __restrict__ cent,
                            float* __restrict__ ncent) {
  const int sIdx = blockIdx.x;
  const int d = threadIdx.x;
  float acc = 0.f;
  for (int u = 0; u < U_; u++) acc += d3[((size_t)sIdx * U_ + u) * D_ + d];
  acc *= (1.f / U_);
  cent[sIdx * D_ + d] = acc;
  __shared__ float red[256];
  float n2 = block_reduce_sum(acc * acc, red);
  if (d == 0) ncent[sIdx] = fmaxf(sqrtf(n2), 1e-8f);
}

__global__ void ge2e_kernel(const float* __restrict__ d3, const float* __restrict__ cent,
                            const float* __restrict__ ncent, const float* __restrict__ loss_w,
                            const float* __restrict__ loss_b, float* __restrict__ accums) {
  const int p = blockIdx.x;
  const int sIdx = p / U_;
  const int d = threadIdx.x;
  __shared__ float red[256];
  __shared__ float sims[S_];

  const float v = d3[(size_t)p * D_ + d];
  const float cs = cent[sIdx * D_ + d];
  const float pc = (cs * U_ - v) * (1.f / (U_ - 1));

  float nv2 = block_reduce_sum(v * v, red);
  float npc2 = block_reduce_sum(pc * pc, red);
  float dotp = block_reduce_sum(v * pc, red);

  const float w = loss_w[0], b = loss_b[0];
  const float na = fmaxf(sqrtf(nv2), 1e-6f);
  const float npc = fmaxf(sqrtf(npc2), 1e-6f);
  const float pos_sim = w * (dotp / (na * npc)) + b;
  const float nd = fmaxf(sqrtf(nv2), 1e-8f);

  for (int k = 0; k < S_; k++) {
    float dk = block_reduce_sum(v * cent[k * D_ + d], red);
    if (d == 0) sims[k] = w * (dk / (nd * ncent[k])) + b;
  }
  __syncthreads();
  if (d == 0) {
    float mx = -1e30f;
    for (int k = 0; k < S_; k++)
      if (k != sIdx) mx = fmaxf(mx, sims[k]);
    float se = 0.f, sn = 0.f;
    for (int k = 0; k < S_; k++)
      if (k != sIdx) { se += expf(sims[k] - mx); sn += sims[k]; }
    float lse = mx + logf(se);
    atomicAdd(&accums[0], -pos_sim + lse);
    atomicAdd(&accums[1], pos_sim);
    atomicAdd(&accums[2], sn);
  }
}

__global__ void finalize_kernel(const float* __restrict__ accums, float* __restrict__ out) {
  if (threadIdx.x == 0) {
    out[0] = accums[0] / (float)(S_ * U_);
    out[1] = accums[1] / (float)(S_ * U_);
    out[2] = accums[2] / (float)(S_ * U_ * (S_ - 1));
  }
}

// ---------------- launch ----------------
extern "C" void kernel_launch(void* const* d_in, const int* in_sizes, int n_in,
                              void* d_out, int out_size, void* d_ws, size_t ws_size,
                              hipStream_t stream) {
  const float* mel = (const float*)d_in[0];
  const float* Wih[3] = {(const float*)d_in[1], (const float*)d_in[5], (const float*)d_in[9]};
  const float* Whh[3] = {(const float*)d_in[2], (const float*)d_in[6], (const float*)d_in[10]};
  const float* bih[3] = {(const float*)d_in[3], (const float*)d_in[7], (const float*)d_in[11]};
  const float* bhh[3] = {(const float*)d_in[4], (const float*)d_in[8], (const float*)d_in[12]};
  const float* Wproj = (const float*)d_in[13];
  const float* bproj = (const float*)d_in[14];
  const float* loss_w = (const float*)d_in[15];
  const float* loss_b = (const float*)d_in[16];
  float* out = (float*)d_out;

  char* ws = (char*)d_ws;
  size_t off = 0;
  auto alloc = [&](size_t bytes) -> void* {
    void* p = ws + off;
    off = (off + bytes + 255) & ~(size_t)255;
    return p;
  };
  _Float16* x0   = (_Float16*)alloc((size_t)B_ * T_ * XP_ * 2);
  _Float16* Wc0  = (_Float16*)alloc((size_t)G4_ * K0_ * 2);
  _Float16* Wc1  = (_Float16*)alloc((size_t)G4_ * K12_ * 2);
  _Float16* Wc2  = (_Float16*)alloc((size_t)G4_ * K12_ * 2);
  float*    bias = (float*)alloc((size_t)3 * G4_ * 4);
  _Float16* hbuf = (_Float16*)alloc((size_t)6 * B_ * H_ * 2);
  float*    d3   = (float*)alloc((size_t)B_ * D_ * 4);
  float*    cent = (float*)alloc((size_t)S_ * D_ * 4);
  float*    ncent = (float*)alloc((size_t)S_ * 4);
  float*    accums = (float*)alloc(64);
  int*      flags = (int*)alloc((size_t)(T_ + 3) * 3 * 96 * 4);

  hipMemsetAsync(hbuf, 0, (size_t)6 * B_ * H_ * 2, stream);
  hipMemsetAsync(accums, 0, 64, stream);
  hipMemsetAsync(flags, 0, (size_t)(T_ + 3) * 3 * 96 * 4, stream);

  prep_x0<<<(B_ * T_ * XP_ + 255) / 256, 256, 0, stream>>>(mel, x0);
  prep_w0<<<(G4_ * K0_ + 255) / 256, 256, 0, stream>>>(Wih[0], Whh[0], Wc0);
  prep_w12<<<(G4_ * K12_ + 255) / 256, 256, 0, stream>>>(Wih[1], Whh[1], Wc1);
  prep_w12<<<(G4_ * K12_ + 255) / 256, 256, 0, stream>>>(Wih[2], Whh[2], Wc2);
  for (int l = 0; l < 3; l++)
    prep_bias<<<(G4_ + 255) / 256, 256, 0, stream>>>(bih[l], bhh[l], bias + l * G4_);

  hipFuncSetAttribute((const void*)lstm_persist,
                      hipFuncAttributeMaxDynamicSharedMemorySize, SMEM_BYTES);
  void* kargs[] = {(void*)&x0, (void*)&Wc0, (void*)&Wc1, (void*)&Wc2,
                   (void*)&bias, (void*)&hbuf, (void*)&flags};
  hipLaunchCooperativeKernel((const void*)lstm_persist, dim3(NBLK), dim3(640),
                             kargs, SMEM_BYTES, stream);

  const _Float16* hlast = hbuf + (size_t)(2 * 2 + 1) * B_ * H_;
  dvec_kernel<<<B_, 256, 0, stream>>>(hlast, Wproj, bproj, d3);
  cent_kernel<<<S_, 256, 0, stream>>>(d3, cent, ncent);
  ge2e_kernel<<<B_, 256, 0, stream>>>(d3, cent, ncent, loss_w, loss_b, accums);
  finalize_kernel<<<1, 64, 0, stream>>>(accums, out);
}